// Round 1
// baseline (531.976 us; speedup 1.0000x reference)
//
#include <hip/hip_runtime.h>

typedef __attribute__((ext_vector_type(4))) float f32x4;
typedef __attribute__((ext_vector_type(8))) short bf16x8;

#define GVOID const __attribute__((address_space(1))) void
#define LVOID __attribute__((address_space(3))) void

__device__ __forceinline__ float bf2f(ushort u){
  union { float f; unsigned int i; } c; c.i = ((unsigned int)u) << 16; return c.f;
}
__device__ __forceinline__ ushort f2bf(float f){
  union { float f; unsigned int i; } c; c.f = f;
  unsigned int r = (c.i + 0x7FFFu + ((c.i >> 16) & 1u)) >> 16;
  return (ushort)r;
}

// ---------------- f32 -> bf16 convert ----------------
__global__ __launch_bounds__(256) void cvtk(const float* __restrict__ s, ushort* __restrict__ d, int n){
  int i = (blockIdx.x * 256 + threadIdx.x) * 4;
  if (i < n){
    float4 v = *(const float4*)(s + i);
    ushort4 o;
    o.x = f2bf(v.x); o.y = f2bf(v.y); o.z = f2bf(v.z); o.w = f2bf(v.w);
    *(ushort4*)(d + i) = o;
  }
}

// ---------------- GEMM: C[M,N] = A[M,K] @ W[N,K]^T + bias (+ residual R) ----------------
// bf16 inputs, f32 MFMA accumulate, bf16 output. Tile 128x64, BK=64, 4 waves (2x2).
#define GM_BM 128
#define GM_BN 64
#define GM_BK 64

__global__ __launch_bounds__(256,2) void gemm_bt(const ushort* __restrict__ A, const ushort* __restrict__ W,
      const float* __restrict__ bias, const ushort* __restrict__ R, ushort* __restrict__ C,
      int M, int N, int K){
  __shared__ ushort As[GM_BM * GM_BK];   // swizzled 16B chunks: phys = c ^ ((c>>3)&7)
  __shared__ ushort Bs[GM_BN * GM_BK];
  const int ntn = N / GM_BN;
  const int tm = blockIdx.x / ntn, tn = blockIdx.x % ntn;
  const int t = threadIdx.x, lane = t & 63, wave = t >> 6;
  const int wr = wave >> 1, wc = wave & 1;
  const int l15 = lane & 15, l4 = lane >> 4;
  const int rowBase = tm * GM_BM, colBase = tn * GM_BN;
  f32x4 acc[4][2] = {};
  for (int k0 = 0; k0 < K; k0 += GM_BK){
    __syncthreads();
    // stage A: 128x64 bf16 = 1024 chunks of 16B
#pragma unroll
    for (int j = 0; j < 4; ++j){
      int cb = j * 256 + wave * 64;
      int p = cb + lane;
      int row = p >> 3;
      int kc = (p & 7) ^ (row & 7);
      const ushort* src = A + (size_t)(rowBase + row) * K + k0 + kc * 8;
      __builtin_amdgcn_global_load_lds((GVOID*)src, (LVOID*)(As + cb * 8), 16, 0, 0);
    }
    // stage B: 64x64 = 512 chunks
#pragma unroll
    for (int j = 0; j < 2; ++j){
      int cb = j * 256 + wave * 64;
      int p = cb + lane;
      int row = p >> 3;
      int kc = (p & 7) ^ (row & 7);
      const ushort* src = W + (size_t)(colBase + row) * K + k0 + kc * 8;
      __builtin_amdgcn_global_load_lds((GVOID*)src, (LVOID*)(Bs + cb * 8), 16, 0, 0);
    }
    __syncthreads();
#pragma unroll
    for (int kk = 0; kk < 2; ++kk){
      bf16x8 a[4], b[2];
#pragma unroll
      for (int m = 0; m < 4; ++m){
        int row = wr * 64 + m * 16 + l15;
        int ch = row * 8 + kk * 4 + l4;
        ch ^= (row & 7);
        a[m] = *(const bf16x8*)(As + ch * 8);
      }
#pragma unroll
      for (int n = 0; n < 2; ++n){
        int row = wc * 32 + n * 16 + l15;
        int ch = row * 8 + kk * 4 + l4;
        ch ^= (row & 7);
        b[n] = *(const bf16x8*)(Bs + ch * 8);
      }
#pragma unroll
      for (int m = 0; m < 4; ++m)
#pragma unroll
      for (int n = 0; n < 2; ++n)
        acc[m][n] = __builtin_amdgcn_mfma_f32_16x16x32_bf16(a[m], b[n], acc[m][n], 0, 0, 0);
    }
  }
  // epilogue: C/D layout row=(lane>>4)*4+r, col=lane&15
#pragma unroll
  for (int m = 0; m < 4; ++m)
#pragma unroll
  for (int n = 0; n < 2; ++n)
#pragma unroll
  for (int r = 0; r < 4; ++r){
    int row = rowBase + wr * 64 + m * 16 + l4 * 4 + r;
    int col = colBase + wc * 32 + n * 16 + l15;
    float v = acc[m][n][r] + bias[col];
    if (R) v += bf2f(R[(size_t)row * N + col]);
    C[(size_t)row * N + col] = f2bf(v);
  }
}

// ---------------- V transpose: Vt[b][n][d][t] = V[b][t][n*64+d] ----------------
__global__ __launch_bounds__(256) void transpose_v(const ushort* __restrict__ V, ushort* __restrict__ Vt){
  int idx = blockIdx.x * 256 + threadIdx.x;   // over [B][N][64][T/8]
  int tc = idx & 127; idx >>= 7;
  int d = idx & 63; idx >>= 6;
  int n = idx & 15; int b = idx >> 4;
  const ushort* src = V + ((size_t)(b * 1024) + tc * 8) * 1024 + n * 64 + d;
  bf16x8 o;
#pragma unroll
  for (int i = 0; i < 8; ++i) o[i] = (short)src[(size_t)i * 1024];
  *(bf16x8*)(Vt + ((size_t)((b * 16 + n) * 64 + d)) * 1024 + tc * 8) = o;
}

// ---------------- fused flash attention ----------------
// Block = (qtile, head, b); 4 waves; wave w owns q rows qt*128 + w*32 .. +31.
// Q,K: [B,T,H] bf16; Vt: [B,N,64,T] bf16; O: [B,T,H] bf16.
__global__ __launch_bounds__(256,2) void attn_kernel(const ushort* __restrict__ Q, const ushort* __restrict__ Kv,
    const ushort* __restrict__ Vt, ushort* __restrict__ O, const int* __restrict__ smask, int causal){
  __shared__ ushort Kt[128 * 64];     // [128 k][64 d], chunk swizzle phys = c ^ ((c>>3)&7)
  __shared__ ushort Vs[64 * 128];     // [64 d][128 k], chunk swizzle phys = c ^ ((c>>4)&7)
  __shared__ ushort Ps[4][32 * 128];  // per-wave P stripe, element swizzle col ^ ((row&7)<<3)
  const int qt = blockIdx.x, head = blockIdx.y, b = blockIdx.z;
  const int t = threadIdx.x, lane = t & 63, wave = t >> 6;
  const int l15 = lane & 15, l4 = lane >> 4;
  const int qr0 = qt * 128 + wave * 32;
  // Q fragments (stay in registers)
  bf16x8 aq[2][2];
#pragma unroll
  for (int m = 0; m < 2; ++m)
#pragma unroll
  for (int kk = 0; kk < 2; ++kk)
    aq[m][kk] = *(const bf16x8*)(Q + (size_t)(b * 1024 + qr0 + m * 16 + l15) * 1024 + head * 64 + kk * 32 + l4 * 8);
  f32x4 cacc[2][4] = {};
  float mrow[2][4], lrow[2][4];
#pragma unroll
  for (int m = 0; m < 2; ++m)
#pragma unroll
  for (int r = 0; r < 4; ++r){ mrow[m][r] = -1e30f; lrow[m][r] = 0.f; }
  const int nkt = causal ? (qt + 1) : 8;
  for (int kt = 0; kt < nkt; ++kt){
    const int k0 = kt * 128;
    __syncthreads();
    // stage K tile [128][64]
#pragma unroll
    for (int j = 0; j < 4; ++j){
      int cb = j * 256 + wave * 64;
      int p = cb + lane;
      int row = p >> 3;
      int kc = (p & 7) ^ (row & 7);
      const ushort* src = Kv + (size_t)(b * 1024 + k0 + row) * 1024 + head * 64 + kc * 8;
      __builtin_amdgcn_global_load_lds((GVOID*)src, (LVOID*)(Kt + cb * 8), 16, 0, 0);
    }
    // stage V^T tile [64][128]
#pragma unroll
    for (int j = 0; j < 4; ++j){
      int cb = j * 256 + wave * 64;
      int p = cb + lane;
      int row = p >> 4;
      int cc = (p & 15) ^ (row & 7);
      const ushort* src = Vt + (size_t)((b * 16 + head) * 64 + row) * 1024 + k0 + cc * 8;
      __builtin_amdgcn_global_load_lds((GVOID*)src, (LVOID*)(Vs + cb * 8), 16, 0, 0);
    }
    __syncthreads();
    // S = Q K^T  (rows: q, cols: k)
    f32x4 s[2][8] = {};
#pragma unroll
    for (int kk = 0; kk < 2; ++kk){
      bf16x8 bk[8];
#pragma unroll
      for (int n = 0; n < 8; ++n){
        int row = n * 16 + l15;
        int ch = row * 8 + kk * 4 + l4;
        ch ^= (row & 7);
        bk[n] = *(const bf16x8*)(Kt + ch * 8);
      }
#pragma unroll
      for (int m = 0; m < 2; ++m)
#pragma unroll
      for (int n = 0; n < 8; ++n)
        s[m][n] = __builtin_amdgcn_mfma_f32_16x16x32_bf16(aq[m][kk], bk[n], s[m][n], 0, 0, 0);
    }
    // masks
    if (causal && kt == qt){
#pragma unroll
      for (int m = 0; m < 2; ++m)
#pragma unroll
      for (int n = 0; n < 8; ++n)
#pragma unroll
      for (int r = 0; r < 4; ++r)
        if (k0 + n * 16 + l15 > qr0 + m * 16 + l4 * 4 + r) s[m][n][r] = -1e6f;
    }
    if (smask){
#pragma unroll
      for (int n = 0; n < 8; ++n){
        int mv = smask[b * 1024 + k0 + n * 16 + l15];
        if (mv == 0){
#pragma unroll
          for (int m = 0; m < 2; ++m)
#pragma unroll
          for (int r = 0; r < 4; ++r) s[m][n][r] = -1e6f;
        }
      }
    }
    // online softmax (row stats within 16-lane groups)
    float scal[2][4], psum[2][4];
#pragma unroll
    for (int m = 0; m < 2; ++m)
#pragma unroll
    for (int r = 0; r < 4; ++r){
      float mx = s[m][0][r];
#pragma unroll
      for (int n = 1; n < 8; ++n) mx = fmaxf(mx, s[m][n][r]);
      mx = fmaxf(mx, __shfl_xor(mx, 1));
      mx = fmaxf(mx, __shfl_xor(mx, 2));
      mx = fmaxf(mx, __shfl_xor(mx, 4));
      mx = fmaxf(mx, __shfl_xor(mx, 8));
      float mn = fmaxf(mrow[m][r], mx);
      scal[m][r] = __expf(mrow[m][r] - mn);
      mrow[m][r] = mn;
      psum[m][r] = 0.f;
    }
#pragma unroll
    for (int m = 0; m < 2; ++m)
#pragma unroll
    for (int n = 0; n < 8; ++n)
#pragma unroll
    for (int r = 0; r < 4; ++r){
      float p = __expf(s[m][n][r] - mrow[m][r]);
      s[m][n][r] = p;
      psum[m][r] += p;
    }
#pragma unroll
    for (int m = 0; m < 2; ++m)
#pragma unroll
    for (int r = 0; r < 4; ++r){
      float ps = psum[m][r];
      ps += __shfl_xor(ps, 1);
      ps += __shfl_xor(ps, 2);
      ps += __shfl_xor(ps, 4);
      ps += __shfl_xor(ps, 8);
      lrow[m][r] = lrow[m][r] * scal[m][r] + ps;
    }
#pragma unroll
    for (int m = 0; m < 2; ++m)
#pragma unroll
    for (int nd = 0; nd < 4; ++nd)
#pragma unroll
    for (int r = 0; r < 4; ++r)
      cacc[m][nd][r] *= scal[m][r];
    // P -> bf16 -> per-wave LDS stripe (layout change C->A)
    ushort* Pw = &Ps[wave][0];
#pragma unroll
    for (int m = 0; m < 2; ++m)
#pragma unroll
    for (int n = 0; n < 8; ++n)
#pragma unroll
    for (int r = 0; r < 4; ++r){
      int rowl = m * 16 + l4 * 4 + r;
      int col = n * 16 + l15;
      Pw[rowl * 128 + (col ^ ((rowl & 7) << 3))] = f2bf(s[m][n][r]);
    }
    // PV: ctx += P @ V  (B operand = rows of V^T)
#pragma unroll
    for (int kk2 = 0; kk2 < 4; ++kk2){
      bf16x8 ap[2], bv[4];
#pragma unroll
      for (int m = 0; m < 2; ++m){
        int rowl = m * 16 + l15;
        int kx = kk2 * 32 + l4 * 8;
        ap[m] = *(const bf16x8*)(Pw + rowl * 128 + (kx ^ ((rowl & 7) << 3)));
      }
#pragma unroll
      for (int nd = 0; nd < 4; ++nd){
        int rowd = nd * 16 + l15;
        int ch = rowd * 16 + kk2 * 4 + l4;
        ch ^= (rowd & 7);
        bv[nd] = *(const bf16x8*)(Vs + ch * 8);
      }
#pragma unroll
      for (int m = 0; m < 2; ++m)
#pragma unroll
      for (int nd = 0; nd < 4; ++nd)
        cacc[m][nd] = __builtin_amdgcn_mfma_f32_16x16x32_bf16(ap[m], bv[nd], cacc[m][nd], 0, 0, 0);
    }
  }
  // epilogue: normalize and store
#pragma unroll
  for (int m = 0; m < 2; ++m)
#pragma unroll
  for (int nd = 0; nd < 4; ++nd)
#pragma unroll
  for (int r = 0; r < 4; ++r){
    int row = qr0 + m * 16 + l4 * 4 + r;
    int col = head * 64 + nd * 16 + l15;
    O[(size_t)(b * 1024 + row) * 1024 + col] = f2bf(cacc[m][nd][r] / lrow[m][r]);
  }
}

// ---------------- LayerNorm over H=1024 ----------------
__global__ __launch_bounds__(256) void ln_kernel(const ushort* __restrict__ X, const float* __restrict__ g,
    const float* __restrict__ bta, ushort* __restrict__ outb, float* __restrict__ outf){
  const int row = blockIdx.x, t = threadIdx.x;
  const ushort* xr = X + (size_t)row * 1024;
  ushort4 u = *(const ushort4*)(xr + t * 4);
  float x0 = bf2f(u.x), x1 = bf2f(u.y), x2 = bf2f(u.z), x3 = bf2f(u.w);
  float s = x0 + x1 + x2 + x3;
  float s2 = x0 * x0 + x1 * x1 + x2 * x2 + x3 * x3;
#pragma unroll
  for (int d = 1; d < 64; d <<= 1){ s += __shfl_xor(s, d); s2 += __shfl_xor(s2, d); }
  __shared__ float red[8];
  const int lane = t & 63, wave = t >> 6;
  if (lane == 0){ red[wave] = s; red[4 + wave] = s2; }
  __syncthreads();
  s = red[0] + red[1] + red[2] + red[3];
  s2 = red[4] + red[5] + red[6] + red[7];
  float mu = s * (1.f / 1024.f);
  float var = fmaxf(s2 * (1.f / 1024.f) - mu * mu, 0.f);
  float rstd = rsqrtf(var + 1e-12f);
  int col = t * 4;
  float y0 = (x0 - mu) * rstd * g[col + 0] + bta[col + 0];
  float y1 = (x1 - mu) * rstd * g[col + 1] + bta[col + 1];
  float y2 = (x2 - mu) * rstd * g[col + 2] + bta[col + 2];
  float y3 = (x3 - mu) * rstd * g[col + 3] + bta[col + 3];
  if (outb){
    ushort4 o; o.x = f2bf(y0); o.y = f2bf(y1); o.z = f2bf(y2); o.w = f2bf(y3);
    *(ushort4*)(outb + (size_t)row * 1024 + col) = o;
  } else {
    float4 o; o.x = y0; o.y = y1; o.z = y2; o.w = y3;
    *(float4*)(outf + (size_t)row * 1024 + col) = o;
  }
}

extern "C" void kernel_launch(void* const* d_in, const int* in_sizes, int n_in,
                              void* d_out, int out_size, void* d_ws, size_t ws_size,
                              hipStream_t stream){
  const float* enc = (const float*)d_in[0];
  const float* dec = (const float*)d_in[1];
  const int* smask = (const int*)d_in[2];
  // d_in[3] = tgt_attn_mask: lower-triangular causal by construction -> computed arithmetically
  const float* q_w  = (const float*)d_in[4];  const float* q_b  = (const float*)d_in[5];
  const float* k_w  = (const float*)d_in[6];  const float* k_b  = (const float*)d_in[7];
  const float* v_w  = (const float*)d_in[8];  const float* v_b  = (const float*)d_in[9];
  const float* sq_w = (const float*)d_in[10]; const float* sq_b = (const float*)d_in[11];
  const float* sk_w = (const float*)d_in[12]; const float* sk_b = (const float*)d_in[13];
  const float* sv_w = (const float*)d_in[14]; const float* sv_b = (const float*)d_in[15];
  const float* dw   = (const float*)d_in[16]; const float* db   = (const float*)d_in[17];
  const float* lng  = (const float*)d_in[18]; const float* lnb  = (const float*)d_in[19];
  ushort* ws = (ushort*)d_ws;
  const size_t MEG = 1024u * 1024u;
  ushort* decb = ws + 0 * MEG;    // [4096,1024] bf16; later reused for self_out
  ushort* encb = ws + 4 * MEG;
  ushort* Qb   = ws + 8 * MEG;    // Q then Q2
  ushort* Kb   = ws + 12 * MEG;   // K then K2
  ushort* Vb   = ws + 16 * MEG;   // V then V2
  ushort* Vtb  = ws + 20 * MEG;   // V^T per head
  ushort* ctx  = ws + 24 * MEG;
  ushort* S1   = ws + 28 * MEG;   // q + proj (LN input)
  ushort* Wq  = ws + 32 * MEG; ushort* Wk  = ws + 33 * MEG; ushort* Wv  = ws + 34 * MEG;
  ushort* Wsq = ws + 35 * MEG; ushort* Wsk = ws + 36 * MEG; ushort* Wsv = ws + 37 * MEG;
  ushort* Wd  = ws + 38 * MEG;
  const int M = 4096, N = 1024, Kd = 1024;
  // converts
  cvtk<<<4096, 256, 0, stream>>>(dec, decb, (int)(4 * MEG));
  cvtk<<<4096, 256, 0, stream>>>(enc, encb, (int)(4 * MEG));
  cvtk<<<1024, 256, 0, stream>>>(q_w,  Wq,  (int)MEG);
  cvtk<<<1024, 256, 0, stream>>>(k_w,  Wk,  (int)MEG);
  cvtk<<<1024, 256, 0, stream>>>(v_w,  Wv,  (int)MEG);
  cvtk<<<1024, 256, 0, stream>>>(sq_w, Wsq, (int)MEG);
  cvtk<<<1024, 256, 0, stream>>>(sk_w, Wsk, (int)MEG);
  cvtk<<<1024, 256, 0, stream>>>(sv_w, Wsv, (int)MEG);
  cvtk<<<1024, 256, 0, stream>>>(dw,   Wd,  (int)MEG);
  // ---- self attention ----
  gemm_bt<<<512, 256, 0, stream>>>(decb, Wq, q_b, nullptr, Qb, M, N, Kd);
  gemm_bt<<<512, 256, 0, stream>>>(decb, Wk, k_b, nullptr, Kb, M, N, Kd);
  gemm_bt<<<512, 256, 0, stream>>>(decb, Wv, v_b, nullptr, Vb, M, N, Kd);
  transpose_v<<<2048, 256, 0, stream>>>(Vb, Vtb);
  attn_kernel<<<dim3(8, 16, 4), 256, 0, stream>>>(Qb, Kb, Vtb, ctx, nullptr, 1);
  gemm_bt<<<512, 256, 0, stream>>>(ctx, Wd, db, Qb, S1, M, N, Kd);       // + residual Q
  ln_kernel<<<4096, 256, 0, stream>>>(S1, lng, lnb, decb, nullptr);      // self_out (bf16) -> decb
  // ---- cross attention ----
  gemm_bt<<<512, 256, 0, stream>>>(decb, Wsq, sq_b, nullptr, Qb, M, N, Kd);
  gemm_bt<<<512, 256, 0, stream>>>(encb, Wsk, sk_b, nullptr, Kb, M, N, Kd);
  gemm_bt<<<512, 256, 0, stream>>>(encb, Wsv, sv_b, nullptr, Vb, M, N, Kd);
  transpose_v<<<2048, 256, 0, stream>>>(Vb, Vtb);
  attn_kernel<<<dim3(8, 16, 4), 256, 0, stream>>>(Qb, Kb, Vtb, ctx, smask, 0);
  gemm_bt<<<512, 256, 0, stream>>>(ctx, Wd, db, Qb, S1, M, N, Kd);       // + residual Q2
  ln_kernel<<<4096, 256, 0, stream>>>(S1, lng, lnb, nullptr, (float*)d_out);
}

// Round 2
// 301.614 us; speedup vs baseline: 1.7638x; 1.7638x over previous
//
#include <hip/hip_runtime.h>

typedef __attribute__((ext_vector_type(4))) float f32x4;
typedef __attribute__((ext_vector_type(8))) short bf16x8;

#define GVOID const __attribute__((address_space(1))) void
#define LVOID __attribute__((address_space(3))) void

__device__ __forceinline__ float bf2f(ushort u){
  union { float f; unsigned int i; } c; c.i = ((unsigned int)u) << 16; return c.f;
}
__device__ __forceinline__ ushort f2bf(float f){
  union { float f; unsigned int i; } c; c.f = f;
  unsigned int r = (c.i + 0x7FFFu + ((c.i >> 16) & 1u)) >> 16;
  return (ushort)r;
}

// ---------------- f32 -> bf16 convert ----------------
__global__ __launch_bounds__(256) void cvtk(const float* __restrict__ s, ushort* __restrict__ d, int n){
  int i = (blockIdx.x * 256 + threadIdx.x) * 4;
  if (i < n){
    float4 v = *(const float4*)(s + i);
    ushort4 o;
    o.x = f2bf(v.x); o.y = f2bf(v.y); o.z = f2bf(v.z); o.w = f2bf(v.w);
    *(ushort4*)(d + i) = o;
  }
}

// ---------------- GEMM: C[M,N] = A[M,K] @ W[N,K]^T + bias ----------------
// 2-phase double-buffered, tile 128x64, BK=64, 4 waves (2x2).
// Supports up to 3 fused matrices (per-block select) and 3 epilogue modes:
//   0 = C row-major + bias ; 1 = +bias +residual R ; 2 = scatter to Vt[b][n][d][t] layout.
struct GemmArgs {
  const ushort* A[3];
  const ushort* W[3];
  const float*  bias[3];
  const ushort* R[3];
  ushort*       C[3];
  int           mode[3];
};

__global__ __launch_bounds__(256,2) void gemm_bt(GemmArgs ga, int nmat, int M, int N, int K){
  __shared__ ushort As[2][128 * 64];
  __shared__ ushort Bs[2][64 * 64];
  const int nb = gridDim.x;
  const int ntn = N >> 6;                    // 16
  const int tq_cnt = ntn * nmat;             // 16 or 48
  const int x = blockIdx.x & 7, ii = blockIdx.x >> 3;
  const int ipx = nb >> 3;                   // blocks per xcd
  const int gpx = ipx / tq_cnt;              // tm-groups per xcd
  const int tm = x * gpx + ii / tq_cnt;
  const int tq = ii % tq_cnt;
  const int g = tq / ntn, tn = tq % ntn;
  const ushort* __restrict__ A = ga.A[g];
  const ushort* __restrict__ W = ga.W[g];
  const float*  __restrict__ bias = ga.bias[g];
  const ushort* __restrict__ R = ga.R[g];
  ushort* __restrict__ C = ga.C[g];
  const int mode = ga.mode[g];

  const int t = threadIdx.x, lane = t & 63, wave = t >> 6;
  const int wr = wave >> 1, wc = wave & 1;
  const int l15 = lane & 15, l4 = lane >> 4;
  const int rowBase = tm * 128, colBase = tn * 64;

  auto stage = [&](int buf, int k0){
#pragma unroll
    for (int j = 0; j < 4; ++j){
      int cb = j * 256 + wave * 64;
      int p = cb + lane;
      int row = p >> 3;
      int kc = (p & 7) ^ (row & 7);
      const ushort* src = A + (size_t)(rowBase + row) * K + k0 + kc * 8;
      __builtin_amdgcn_global_load_lds((GVOID*)src, (LVOID*)(&As[buf][cb * 8]), 16, 0, 0);
    }
#pragma unroll
    for (int j = 0; j < 2; ++j){
      int cb = j * 256 + wave * 64;
      int p = cb + lane;
      int row = p >> 3;
      int kc = (p & 7) ^ (row & 7);
      const ushort* src = W + (size_t)(colBase + row) * K + k0 + kc * 8;
      __builtin_amdgcn_global_load_lds((GVOID*)src, (LVOID*)(&Bs[buf][cb * 8]), 16, 0, 0);
    }
  };

  f32x4 acc[4][2] = {};
  const int NT = K >> 6;
  stage(0, 0);
  __syncthreads();
  for (int tk = 0; tk < NT; ++tk){
    const int cur = tk & 1;
    if (tk + 1 < NT) stage(cur ^ 1, (tk + 1) * 64);
#pragma unroll
    for (int kk = 0; kk < 2; ++kk){
      bf16x8 a[4], b[2];
#pragma unroll
      for (int m = 0; m < 4; ++m){
        int row = wr * 64 + m * 16 + l15;
        int ch = row * 8 + kk * 4 + l4;
        ch ^= (row & 7);
        a[m] = *(const bf16x8*)(&As[cur][ch * 8]);
      }
#pragma unroll
      for (int n = 0; n < 2; ++n){
        int row = wc * 32 + n * 16 + l15;
        int ch = row * 8 + kk * 4 + l4;
        ch ^= (row & 7);
        b[n] = *(const bf16x8*)(&Bs[cur][ch * 8]);
      }
#pragma unroll
      for (int m = 0; m < 4; ++m)
#pragma unroll
      for (int n = 0; n < 2; ++n)
        acc[m][n] = __builtin_amdgcn_mfma_f32_16x16x32_bf16(a[m], b[n], acc[m][n], 0, 0, 0);
    }
    __syncthreads();
  }
  // epilogue
#pragma unroll
  for (int m = 0; m < 4; ++m)
#pragma unroll
  for (int n = 0; n < 2; ++n)
#pragma unroll
  for (int r = 0; r < 4; ++r){
    int row = rowBase + wr * 64 + m * 16 + l4 * 4 + r;
    int col = colBase + wc * 32 + n * 16 + l15;
    float v = acc[m][n][r] + bias[col];
    if (mode == 1) v += bf2f(R[(size_t)row * N + col]);
    if (mode == 2){
      int bb = row >> 10, tt = row & 1023, nh = col >> 6, d = col & 63;
      C[((size_t)((bb * 16 + nh) * 64 + d)) * 1024 + tt] = f2bf(v);
    } else {
      C[(size_t)row * N + col] = f2bf(v);
    }
  }
}

// ---------------- fused flash attention ----------------
// 1-D grid of 1024 blocks, XCD-swizzled so the 16 q-tiles of one (b,head)
// share an XCD (K/V stay L2-resident). 4 waves/block, 16 q-rows per wave.
// Q,K: [B,T,H] bf16; Vt: [B,N,64,T] bf16; O: [B,T,H] bf16.
__global__ __launch_bounds__(256,4) void attn_kernel(const ushort* __restrict__ Q, const ushort* __restrict__ Kv,
    const ushort* __restrict__ Vt, ushort* __restrict__ O, const int* __restrict__ smask, int causal){
  __shared__ ushort Kt[128 * 64];       // [128 k][64 d], chunk swizzle
  __shared__ ushort Vs[64 * 128];       // [64 d][128 k], chunk swizzle
  __shared__ ushort Ps[4][2][16 * 32];  // per-wave P chunk, double-buffered, word swizzle
  const int p = blockIdx.x;
  const int x = p & 7, ii = p >> 3;
  const int g = x * 8 + (ii >> 4);      // (b,head) group co-located per XCD
  const int qt = ii & 15;
  const int b = g >> 4, head = g & 15;
  const int t = threadIdx.x, lane = t & 63, wave = t >> 6;
  const int l15 = lane & 15, l4 = lane >> 4;
  const int qr0 = qt * 64 + wave * 16;
  // Q fragments (registers, loaded once)
  bf16x8 aq[2];
#pragma unroll
  for (int kk = 0; kk < 2; ++kk)
    aq[kk] = *(const bf16x8*)(Q + (size_t)(b * 1024 + qr0 + l15) * 1024 + head * 64 + kk * 32 + l4 * 8);
  f32x4 cacc[4] = {};
  float mrow[4], lrow[4];
#pragma unroll
  for (int r = 0; r < 4; ++r){ mrow[r] = -1e30f; lrow[r] = 0.f; }
  const int nkt = causal ? ((qt >> 1) + 1) : 8;
  for (int kt = 0; kt < nkt; ++kt){
    const int k0 = kt * 128;
    __syncthreads();
    // stage K tile [128][64]
#pragma unroll
    for (int j = 0; j < 4; ++j){
      int cb = j * 256 + wave * 64;
      int pp = cb + lane;
      int row = pp >> 3;
      int kc = (pp & 7) ^ (row & 7);
      const ushort* src = Kv + (size_t)(b * 1024 + k0 + row) * 1024 + head * 64 + kc * 8;
      __builtin_amdgcn_global_load_lds((GVOID*)src, (LVOID*)(Kt + cb * 8), 16, 0, 0);
    }
    // stage V^T tile [64][128]
#pragma unroll
    for (int j = 0; j < 4; ++j){
      int cb = j * 256 + wave * 64;
      int pp = cb + lane;
      int row = pp >> 4;
      int cc = (pp & 15) ^ (row & 7);
      const ushort* src = Vt + (size_t)((b * 16 + head) * 64 + row) * 1024 + k0 + cc * 8;
      __builtin_amdgcn_global_load_lds((GVOID*)src, (LVOID*)(Vs + cb * 8), 16, 0, 0);
    }
    __syncthreads();
    // S = Q K^T (16 q rows x 128 k cols)
    f32x4 s[8] = {};
#pragma unroll
    for (int kk = 0; kk < 2; ++kk){
      bf16x8 bk[8];
#pragma unroll
      for (int n = 0; n < 8; ++n){
        int row = n * 16 + l15;
        int ch = row * 8 + kk * 4 + l4;
        ch ^= (row & 7);
        bk[n] = *(const bf16x8*)(Kt + ch * 8);
      }
#pragma unroll
      for (int n = 0; n < 8; ++n)
        s[n] = __builtin_amdgcn_mfma_f32_16x16x32_bf16(aq[kk], bk[n], s[n], 0, 0, 0);
    }
    // masks
    if (causal && kt == (qt >> 1)){
#pragma unroll
      for (int n = 0; n < 8; ++n)
#pragma unroll
      for (int r = 0; r < 4; ++r)
        if (k0 + n * 16 + l15 > qr0 + l4 * 4 + r) s[n][r] = -1e6f;
    }
    if (smask){
#pragma unroll
      for (int n = 0; n < 8; ++n){
        int mv = smask[b * 1024 + k0 + n * 16 + l15];
        if (mv == 0){
#pragma unroll
          for (int r = 0; r < 4; ++r) s[n][r] = -1e6f;
        }
      }
    }
    // online softmax (each lane owns rows l4*4+r, reduce over cols = n x l15)
    float scal[4];
#pragma unroll
    for (int r = 0; r < 4; ++r){
      float mx = s[0][r];
#pragma unroll
      for (int n = 1; n < 8; ++n) mx = fmaxf(mx, s[n][r]);
      mx = fmaxf(mx, __shfl_xor(mx, 1));
      mx = fmaxf(mx, __shfl_xor(mx, 2));
      mx = fmaxf(mx, __shfl_xor(mx, 4));
      mx = fmaxf(mx, __shfl_xor(mx, 8));
      float mn = fmaxf(mrow[r], mx);
      scal[r] = __expf(mrow[r] - mn);
      mrow[r] = mn;
    }
    float psum[4] = {0.f, 0.f, 0.f, 0.f};
#pragma unroll
    for (int n = 0; n < 8; ++n)
#pragma unroll
    for (int r = 0; r < 4; ++r){
      float pv = __expf(s[n][r] - mrow[r]);
      s[n][r] = pv;
      psum[r] += pv;
    }
#pragma unroll
    for (int r = 0; r < 4; ++r){
      float ps = psum[r];
      ps += __shfl_xor(ps, 1);
      ps += __shfl_xor(ps, 2);
      ps += __shfl_xor(ps, 4);
      ps += __shfl_xor(ps, 8);
      lrow[r] = lrow[r] * scal[r] + ps;
    }
#pragma unroll
    for (int nd = 0; nd < 4; ++nd)
#pragma unroll
    for (int r = 0; r < 4; ++r)
      cacc[nd][r] *= scal[r];
    // PV in 4 chunks of 32 k-cols: stage P chunk -> LDS -> A-frag -> 4 MFMA
#pragma unroll
    for (int kk2 = 0; kk2 < 4; ++kk2){
      ushort* Pw = &Ps[wave][kk2 & 1][0];
#pragma unroll
      for (int n2 = 0; n2 < 2; ++n2){
        int n = kk2 * 2 + n2;
#pragma unroll
        for (int r = 0; r < 4; ++r){
          int rowl = l4 * 4 + r;
          int c = n2 * 16 + l15;
          int w = (c >> 1) ^ ((rowl & 3) << 2);
          Pw[(rowl * 16 + w) * 2 + (c & 1)] = f2bf(s[n][r]);
        }
      }
      bf16x8 ap, bv[4];
      {
        int rowl = l15;
        int w0 = (l4 * 4) ^ ((rowl & 3) << 2);
        ap = *(const bf16x8*)(Pw + (rowl * 16 + w0) * 2);
      }
#pragma unroll
      for (int nd = 0; nd < 4; ++nd){
        int rowd = nd * 16 + l15;
        int ch = rowd * 16 + kk2 * 4 + l4;
        ch ^= (rowd & 7);
        bv[nd] = *(const bf16x8*)(Vs + ch * 8);
      }
#pragma unroll
      for (int nd = 0; nd < 4; ++nd)
        cacc[nd] = __builtin_amdgcn_mfma_f32_16x16x32_bf16(ap, bv[nd], cacc[nd], 0, 0, 0);
    }
  }
  // epilogue
#pragma unroll
  for (int nd = 0; nd < 4; ++nd)
#pragma unroll
  for (int r = 0; r < 4; ++r){
    int row = qr0 + l4 * 4 + r;
    int col = head * 64 + nd * 16 + l15;
    O[(size_t)(b * 1024 + row) * 1024 + col] = f2bf(cacc[nd][r] / lrow[r]);
  }
}

// ---------------- LayerNorm over H=1024 ----------------
__global__ __launch_bounds__(256) void ln_kernel(const ushort* __restrict__ X, const float* __restrict__ g,
    const float* __restrict__ bta, ushort* __restrict__ outb, float* __restrict__ outf){
  const int row = blockIdx.x, t = threadIdx.x;
  const ushort* xr = X + (size_t)row * 1024;
  ushort4 u = *(const ushort4*)(xr + t * 4);
  float x0 = bf2f(u.x), x1 = bf2f(u.y), x2 = bf2f(u.z), x3 = bf2f(u.w);
  float s = x0 + x1 + x2 + x3;
  float s2 = x0 * x0 + x1 * x1 + x2 * x2 + x3 * x3;
#pragma unroll
  for (int d = 1; d < 64; d <<= 1){ s += __shfl_xor(s, d); s2 += __shfl_xor(s2, d); }
  __shared__ float red[8];
  const int lane = t & 63, wave = t >> 6;
  if (lane == 0){ red[wave] = s; red[4 + wave] = s2; }
  __syncthreads();
  s = red[0] + red[1] + red[2] + red[3];
  s2 = red[4] + red[5] + red[6] + red[7];
  float mu = s * (1.f / 1024.f);
  float var = fmaxf(s2 * (1.f / 1024.f) - mu * mu, 0.f);
  float rstd = rsqrtf(var + 1e-12f);
  int col = t * 4;
  float y0 = (x0 - mu) * rstd * g[col + 0] + bta[col + 0];
  float y1 = (x1 - mu) * rstd * g[col + 1] + bta[col + 1];
  float y2 = (x2 - mu) * rstd * g[col + 2] + bta[col + 2];
  float y3 = (x3 - mu) * rstd * g[col + 3] + bta[col + 3];
  if (outb){
    ushort4 o; o.x = f2bf(y0); o.y = f2bf(y1); o.z = f2bf(y2); o.w = f2bf(y3);
    *(ushort4*)(outb + (size_t)row * 1024 + col) = o;
  } else {
    float4 o; o.x = y0; o.y = y1; o.z = y2; o.w = y3;
    *(float4*)(outf + (size_t)row * 1024 + col) = o;
  }
}

extern "C" void kernel_launch(void* const* d_in, const int* in_sizes, int n_in,
                              void* d_out, int out_size, void* d_ws, size_t ws_size,
                              hipStream_t stream){
  const float* enc = (const float*)d_in[0];
  const float* dec = (const float*)d_in[1];
  const int* smask = (const int*)d_in[2];
  // d_in[3] = tgt_attn_mask: lower-triangular causal by construction -> computed arithmetically
  const float* q_w  = (const float*)d_in[4];  const float* q_b  = (const float*)d_in[5];
  const float* k_w  = (const float*)d_in[6];  const float* k_b  = (const float*)d_in[7];
  const float* v_w  = (const float*)d_in[8];  const float* v_b  = (const float*)d_in[9];
  const float* sq_w = (const float*)d_in[10]; const float* sq_b = (const float*)d_in[11];
  const float* sk_w = (const float*)d_in[12]; const float* sk_b = (const float*)d_in[13];
  const float* sv_w = (const float*)d_in[14]; const float* sv_b = (const float*)d_in[15];
  const float* dw   = (const float*)d_in[16]; const float* db   = (const float*)d_in[17];
  const float* lng  = (const float*)d_in[18]; const float* lnb  = (const float*)d_in[19];
  ushort* ws = (ushort*)d_ws;
  const size_t MEG = 1024u * 1024u;
  ushort* decb = ws + 0 * MEG;    // [4096,1024] bf16; later self_out
  ushort* encb = ws + 4 * MEG;
  ushort* Qb   = ws + 8 * MEG;    // Q then Q2
  ushort* Kb   = ws + 12 * MEG;   // K then K2
  ushort* Vtb  = ws + 20 * MEG;   // V^T per head [B][N][64][T]
  ushort* ctx  = ws + 24 * MEG;
  ushort* S1   = ws + 28 * MEG;   // LN input
  ushort* Wq  = ws + 32 * MEG; ushort* Wk  = ws + 33 * MEG; ushort* Wv  = ws + 34 * MEG;
  ushort* Wsq = ws + 35 * MEG; ushort* Wsk = ws + 36 * MEG; ushort* Wsv = ws + 37 * MEG;
  ushort* Wd  = ws + 38 * MEG;
  const int M = 4096, N = 1024, Kd = 1024;
  // converts
  cvtk<<<4096, 256, 0, stream>>>(dec, decb, (int)(4 * MEG));
  cvtk<<<4096, 256, 0, stream>>>(enc, encb, (int)(4 * MEG));
  cvtk<<<1024, 256, 0, stream>>>(q_w,  Wq,  (int)MEG);
  cvtk<<<1024, 256, 0, stream>>>(k_w,  Wk,  (int)MEG);
  cvtk<<<1024, 256, 0, stream>>>(v_w,  Wv,  (int)MEG);
  cvtk<<<1024, 256, 0, stream>>>(sq_w, Wsq, (int)MEG);
  cvtk<<<1024, 256, 0, stream>>>(sk_w, Wsk, (int)MEG);
  cvtk<<<1024, 256, 0, stream>>>(sv_w, Wsv, (int)MEG);
  cvtk<<<1024, 256, 0, stream>>>(dw,   Wd,  (int)MEG);
  // ---- self attention ----
  {
    GemmArgs ga;
    ga.A[0] = decb; ga.A[1] = decb; ga.A[2] = decb;
    ga.W[0] = Wq;   ga.W[1] = Wk;   ga.W[2] = Wv;
    ga.bias[0] = q_b; ga.bias[1] = k_b; ga.bias[2] = v_b;
    ga.R[0] = nullptr; ga.R[1] = nullptr; ga.R[2] = nullptr;
    ga.C[0] = Qb;   ga.C[1] = Kb;   ga.C[2] = Vtb;
    ga.mode[0] = 0; ga.mode[1] = 0; ga.mode[2] = 2;
    gemm_bt<<<1536, 256, 0, stream>>>(ga, 3, M, N, Kd);
  }
  attn_kernel<<<1024, 256, 0, stream>>>(Qb, Kb, Vtb, ctx, nullptr, 1);
  {
    GemmArgs ga = {};
    ga.A[0] = ctx; ga.W[0] = Wd; ga.bias[0] = db; ga.R[0] = Qb; ga.C[0] = S1; ga.mode[0] = 1;
    gemm_bt<<<512, 256, 0, stream>>>(ga, 1, M, N, Kd);
  }
  ln_kernel<<<4096, 256, 0, stream>>>(S1, lng, lnb, decb, nullptr);   // self_out -> decb
  // ---- cross attention ----
  {
    GemmArgs ga;
    ga.A[0] = decb; ga.A[1] = encb; ga.A[2] = encb;
    ga.W[0] = Wsq;  ga.W[1] = Wsk;  ga.W[2] = Wsv;
    ga.bias[0] = sq_b; ga.bias[1] = sk_b; ga.bias[2] = sv_b;
    ga.R[0] = nullptr; ga.R[1] = nullptr; ga.R[2] = nullptr;
    ga.C[0] = Qb;   ga.C[1] = Kb;   ga.C[2] = Vtb;
    ga.mode[0] = 0; ga.mode[1] = 0; ga.mode[2] = 2;
    gemm_bt<<<1536, 256, 0, stream>>>(ga, 3, M, N, Kd);
  }
  attn_kernel<<<1024, 256, 0, stream>>>(Qb, Kb, Vtb, ctx, smask, 0);
  {
    GemmArgs ga = {};
    ga.A[0] = ctx; ga.W[0] = Wd; ga.bias[0] = db; ga.R[0] = Qb; ga.C[0] = S1; ga.mode[0] = 1;
    gemm_bt<<<512, 256, 0, stream>>>(ga, 1, M, N, Kd);
  }
  ln_kernel<<<4096, 256, 0, stream>>>(S1, lng, lnb, nullptr, (float*)d_out);
}

// Round 3
// 262.229 us; speedup vs baseline: 2.0287x; 1.1502x over previous
//
#include <hip/hip_runtime.h>

typedef __attribute__((ext_vector_type(4))) float f32x4;
typedef __attribute__((ext_vector_type(8))) short bf16x8;

#define GVOID const __attribute__((address_space(1))) void
#define LVOID __attribute__((address_space(3))) void

__device__ __forceinline__ float bf2f(ushort u){
  union { float f; unsigned int i; } c; c.i = ((unsigned int)u) << 16; return c.f;
}
__device__ __forceinline__ ushort f2bf(float f){
  union { float f; unsigned int i; } c; c.f = f;
  unsigned int r = (c.i + 0x7FFFu + ((c.i >> 16) & 1u)) >> 16;
  return (ushort)r;
}

// ---------------- f32 -> bf16 convert ----------------
__global__ __launch_bounds__(256) void cvtk(const float* __restrict__ s, ushort* __restrict__ d, int n){
  int i = (blockIdx.x * 256 + threadIdx.x) * 4;
  if (i < n){
    float4 v = *(const float4*)(s + i);
    ushort4 o;
    o.x = f2bf(v.x); o.y = f2bf(v.y); o.z = f2bf(v.z); o.w = f2bf(v.w);
    *(ushort4*)(d + i) = o;
  }
}

// ---------------- GEMM: C[M,N] = A[M,K] @ W[N,K]^T + bias ----------------
struct GemmArgs {
  const ushort* A[3];
  const ushort* W[3];
  const float*  bias[3];
  const ushort* R[3];
  ushort*       C[3];
  int           mode[3];
};

__global__ __launch_bounds__(256,2) void gemm_bt(GemmArgs ga, int nmat, int M, int N, int K){
  __shared__ ushort As[2][128 * 64];
  __shared__ ushort Bs[2][64 * 64];
  const int nb = gridDim.x;
  const int ntn = N >> 6;
  const int tq_cnt = ntn * nmat;
  const int x = blockIdx.x & 7, ii = blockIdx.x >> 3;
  const int ipx = nb >> 3;
  const int gpx = ipx / tq_cnt;
  const int tm = x * gpx + ii / tq_cnt;
  const int tq = ii % tq_cnt;
  const int g = tq / ntn, tn = tq % ntn;
  const ushort* __restrict__ A = ga.A[g];
  const ushort* __restrict__ W = ga.W[g];
  const float*  __restrict__ bias = ga.bias[g];
  const ushort* __restrict__ R = ga.R[g];
  ushort* __restrict__ C = ga.C[g];
  const int mode = ga.mode[g];

  const int t = threadIdx.x, lane = t & 63, wave = t >> 6;
  const int wr = wave >> 1, wc = wave & 1;
  const int l15 = lane & 15, l4 = lane >> 4;
  const int rowBase = tm * 128, colBase = tn * 64;

  auto stage = [&](int buf, int k0){
#pragma unroll
    for (int j = 0; j < 4; ++j){
      int cb = j * 256 + wave * 64;
      int p = cb + lane;
      int row = p >> 3;
      int kc = (p & 7) ^ (row & 7);
      const ushort* src = A + (size_t)(rowBase + row) * K + k0 + kc * 8;
      __builtin_amdgcn_global_load_lds((GVOID*)src, (LVOID*)(&As[buf][cb * 8]), 16, 0, 0);
    }
#pragma unroll
    for (int j = 0; j < 2; ++j){
      int cb = j * 256 + wave * 64;
      int p = cb + lane;
      int row = p >> 3;
      int kc = (p & 7) ^ (row & 7);
      const ushort* src = W + (size_t)(colBase + row) * K + k0 + kc * 8;
      __builtin_amdgcn_global_load_lds((GVOID*)src, (LVOID*)(&Bs[buf][cb * 8]), 16, 0, 0);
    }
  };

  f32x4 acc[4][2] = {};
  const int NT = K >> 6;
  stage(0, 0);
  __syncthreads();
  for (int tk = 0; tk < NT; ++tk){
    const int cur = tk & 1;
    if (tk + 1 < NT) stage(cur ^ 1, (tk + 1) * 64);
#pragma unroll
    for (int kk = 0; kk < 2; ++kk){
      bf16x8 a[4], b[2];
#pragma unroll
      for (int m = 0; m < 4; ++m){
        int row = wr * 64 + m * 16 + l15;
        int ch = row * 8 + kk * 4 + l4;
        ch ^= (row & 7);
        a[m] = *(const bf16x8*)(&As[cur][ch * 8]);
      }
#pragma unroll
      for (int n = 0; n < 2; ++n){
        int row = wc * 32 + n * 16 + l15;
        int ch = row * 8 + kk * 4 + l4;
        ch ^= (row & 7);
        b[n] = *(const bf16x8*)(&Bs[cur][ch * 8]);
      }
#pragma unroll
      for (int m = 0; m < 4; ++m)
#pragma unroll
      for (int n = 0; n < 2; ++n)
        acc[m][n] = __builtin_amdgcn_mfma_f32_16x16x32_bf16(a[m], b[n], acc[m][n], 0, 0, 0);
    }
    __syncthreads();
  }
#pragma unroll
  for (int m = 0; m < 4; ++m)
#pragma unroll
  for (int n = 0; n < 2; ++n)
#pragma unroll
  for (int r = 0; r < 4; ++r){
    int row = rowBase + wr * 64 + m * 16 + l4 * 4 + r;
    int col = colBase + wc * 32 + n * 16 + l15;
    float v = acc[m][n][r] + bias[col];
    if (mode == 1) v += bf2f(R[(size_t)row * N + col]);
    if (mode == 2){
      int bb = row >> 10, tt = row & 1023, nh = col >> 6, d = col & 63;
      C[((size_t)((bb * 16 + nh) * 64 + d)) * 1024 + tt] = f2bf(v);
    } else {
      C[(size_t)row * N + col] = f2bf(v);
    }
  }
}

// ---------------- fused flash attention v3 ----------------
// 512 blocks (4 waves, 128 q-rows; wave owns 32 rows). Swapped QK^T (S^T),
// per-lane-q softmax, vectorized P staging, 2-phase double-buffered K/V LDS.
// Q,K: [B,T,H] bf16; Vt: [B*16+n][64][T] bf16; O: [B,T,H] bf16.
__global__ __launch_bounds__(256,2) void attn_kernel(const ushort* __restrict__ Q, const ushort* __restrict__ Kv,
    const ushort* __restrict__ Vt, ushort* __restrict__ O, const int* __restrict__ smask, int causal){
  __shared__ ushort Ks[2][64 * 64];          // [k 64][d 64], chunk swizzle
  __shared__ ushort Vs[2][64 * 64];          // [d 64][k 64], chunk swizzle
  __shared__ __align__(16) char Ps[4][4096]; // per-wave P^ [32 q][64 k] bf16, byte-XOR swizzle
  const int p = blockIdx.x;
  const int x = p & 7, j = p >> 3;           // XCD, local index 0..63
  const int gg = x * 8 + (j & 7);            // (b,head), co-located per XCD
  const int b = gg >> 4, head = gg & 15;
  const int c3 = (j >> 3) & 3, rr = j >> 5;  // residency round pairing for causal balance
  const int qt = causal ? (rr ? (7 - c3) : c3) : (j >> 3);
  const int t = threadIdx.x, lane = t & 63, wave = t >> 6;
  const int l15 = lane & 15, l4 = lane >> 4;
  const int qr0 = qt * 128 + wave * 32;
  const int sw = (l15 & 7) << 3;

  // Q fragments (B-operand: l15 = q, l4*8 = d)
  bf16x8 aq[2][2];
#pragma unroll
  for (int m = 0; m < 2; ++m)
#pragma unroll
  for (int kk = 0; kk < 2; ++kk)
    aq[m][kk] = *(const bf16x8*)(Q + (size_t)(b * 1024 + qr0 + m * 16 + l15) * 1024 + head * 64 + kk * 32 + l4 * 8);

  f32x4 cacc[2][4] = {};
  float mrow[2] = {-1e30f, -1e30f}, lrow[2] = {0.f, 0.f};

  auto stage = [&](int buf, int k0){
#pragma unroll
    for (int jj = 0; jj < 2; ++jj){
      int cb = jj * 256 + wave * 64;
      int pp = cb + lane;
      int row = pp >> 3;
      int kc = (pp & 7) ^ (row & 7);
      const ushort* src = Kv + (size_t)(b * 1024 + k0 + row) * 1024 + head * 64 + kc * 8;
      __builtin_amdgcn_global_load_lds((GVOID*)src, (LVOID*)(&Ks[buf][cb * 8]), 16, 0, 0);
    }
#pragma unroll
    for (int jj = 0; jj < 2; ++jj){
      int cb = jj * 256 + wave * 64;
      int pp = cb + lane;
      int row = pp >> 3;
      int kc = (pp & 7) ^ (row & 7);
      const ushort* src = Vt + (size_t)((b * 16 + head) * 64 + row) * 1024 + k0 + kc * 8;
      __builtin_amdgcn_global_load_lds((GVOID*)src, (LVOID*)(&Vs[buf][cb * 8]), 16, 0, 0);
    }
  };

  const int nkt = causal ? (2 * qt + 2) : 16;
  stage(0, 0);
  __syncthreads();
  char* Pb = &Ps[wave][0];
  for (int kt = 0; kt < nkt; ++kt){
    const int cur = kt & 1;
    const int k0 = kt * 64;
    if (kt + 1 < nkt) stage(cur ^ 1, (kt + 1) * 64);
    const ushort* Kb_ = &Ks[cur][0];
    const ushort* Vb_ = &Vs[cur][0];
    // S^T = K Q^T : rows k (l4*4+r), cols q (l15)
    f32x4 st[2][4] = {};
#pragma unroll
    for (int kk = 0; kk < 2; ++kk){
      bf16x8 ak[4];
#pragma unroll
      for (int n = 0; n < 4; ++n){
        int row = n * 16 + l15;
        int ch = row * 8 + ((kk * 4 + l4) ^ (row & 7));
        ak[n] = *(const bf16x8*)(Kb_ + ch * 8);
      }
#pragma unroll
      for (int m = 0; m < 2; ++m)
#pragma unroll
      for (int n = 0; n < 4; ++n)
        st[m][n] = __builtin_amdgcn_mfma_f32_16x16x32_bf16(ak[n], aq[m][kk], st[m][n], 0, 0, 0);
    }
    // masks (k per-lane = k0 + n*16 + l4*4 + r ; q = qr0 + m*16 + l15)
    if (causal && k0 + 63 > qr0){
#pragma unroll
      for (int m = 0; m < 2; ++m)
#pragma unroll
      for (int n = 0; n < 4; ++n)
#pragma unroll
      for (int r = 0; r < 4; ++r)
        if (k0 + n * 16 + l4 * 4 + r > qr0 + m * 16 + l15) st[m][n][r] = -1e6f;
    }
    if (smask){
#pragma unroll
      for (int n = 0; n < 4; ++n)
#pragma unroll
      for (int r = 0; r < 4; ++r){
        int mv = smask[b * 1024 + k0 + n * 16 + l4 * 4 + r];
        if (mv == 0){ st[0][n][r] = -1e6f; st[1][n][r] = -1e6f; }
      }
    }
    // online softmax: lane owns one q (=l15) per m; reduce across l4 groups
    float scal[2];
#pragma unroll
    for (int m = 0; m < 2; ++m){
      float mx = st[m][0][0];
#pragma unroll
      for (int n = 0; n < 4; ++n)
#pragma unroll
      for (int r = 0; r < 4; ++r) mx = fmaxf(mx, st[m][n][r]);
      mx = fmaxf(mx, __shfl_xor(mx, 16));
      mx = fmaxf(mx, __shfl_xor(mx, 32));
      float mn = fmaxf(mrow[m], mx);
      scal[m] = __expf(mrow[m] - mn);
      mrow[m] = mn;
      float ps = 0.f;
#pragma unroll
      for (int n = 0; n < 4; ++n)
#pragma unroll
      for (int r = 0; r < 4; ++r){
        float pv = __expf(st[m][n][r] - mn);
        st[m][n][r] = pv;
        ps += pv;
      }
      ps += __shfl_xor(ps, 16);
      ps += __shfl_xor(ps, 32);
      lrow[m] = lrow[m] * scal[m] + ps;
    }
    // broadcast scal to cacc row-domain (q = l4*4+r) and rescale
#pragma unroll
    for (int m = 0; m < 2; ++m)
#pragma unroll
    for (int r = 0; r < 4; ++r){
      float sb = __shfl(scal[m], l4 * 4 + r);
#pragma unroll
      for (int nd = 0; nd < 4; ++nd) cacc[m][nd][r] *= sb;
    }
    // P -> bf16 -> per-wave LDS stripe (vectorized b64, swizzled)
#pragma unroll
    for (int m = 0; m < 2; ++m)
#pragma unroll
    for (int n = 0; n < 4; ++n){
      unsigned lo = (unsigned)f2bf(st[m][n][0]) | ((unsigned)f2bf(st[m][n][1]) << 16);
      unsigned hi = (unsigned)f2bf(st[m][n][2]) | ((unsigned)f2bf(st[m][n][3]) << 16);
      unsigned long long pk = (unsigned long long)lo | ((unsigned long long)hi << 32);
      *(unsigned long long*)(Pb + m * 2048 + l15 * 128 + ((n * 32 + l4 * 8) ^ sw)) = pk;
    }
    // PV: A = P (rows q), B = V^T rows d
#pragma unroll
    for (int ks = 0; ks < 2; ++ks){
      bf16x8 bv[4];
#pragma unroll
      for (int nd = 0; nd < 4; ++nd){
        int row = nd * 16 + l15;
        int ch = row * 8 + ((ks * 4 + l4) ^ (row & 7));
        bv[nd] = *(const bf16x8*)(Vb_ + ch * 8);
      }
#pragma unroll
      for (int m = 0; m < 2; ++m){
        int base = m * 2048 + l15 * 128;
        int o = ks * 64 + l4 * 16;
        union { bf16x8 v; unsigned long long u[2]; } pa;
        pa.u[0] = *(const unsigned long long*)(Pb + base + ((o    ) ^ sw));
        pa.u[1] = *(const unsigned long long*)(Pb + base + ((o + 8) ^ sw));
#pragma unroll
        for (int nd = 0; nd < 4; ++nd)
          cacc[m][nd] = __builtin_amdgcn_mfma_f32_16x16x32_bf16(pa.v, bv[nd], cacc[m][nd], 0, 0, 0);
      }
    }
    __syncthreads();
  }
  // epilogue
#pragma unroll
  for (int m = 0; m < 2; ++m)
#pragma unroll
  for (int r = 0; r < 4; ++r){
    float lb = __shfl(lrow[m], l4 * 4 + r);
    float inv = 1.f / lb;
    int row = qr0 + m * 16 + l4 * 4 + r;
#pragma unroll
    for (int nd = 0; nd < 4; ++nd){
      int col = head * 64 + nd * 16 + l15;
      O[(size_t)(b * 1024 + row) * 1024 + col] = f2bf(cacc[m][nd][r] * inv);
    }
  }
}

// ---------------- LayerNorm over H=1024 ----------------
__global__ __launch_bounds__(256) void ln_kernel(const ushort* __restrict__ X, const float* __restrict__ g,
    const float* __restrict__ bta, ushort* __restrict__ outb, float* __restrict__ outf){
  const int row = blockIdx.x, t = threadIdx.x;
  const ushort* xr = X + (size_t)row * 1024;
  ushort4 u = *(const ushort4*)(xr + t * 4);
  float x0 = bf2f(u.x), x1 = bf2f(u.y), x2 = bf2f(u.z), x3 = bf2f(u.w);
  float s = x0 + x1 + x2 + x3;
  float s2 = x0 * x0 + x1 * x1 + x2 * x2 + x3 * x3;
#pragma unroll
  for (int d = 1; d < 64; d <<= 1){ s += __shfl_xor(s, d); s2 += __shfl_xor(s2, d); }
  __shared__ float red[8];
  const int lane = t & 63, wave = t >> 6;
  if (lane == 0){ red[wave] = s; red[4 + wave] = s2; }
  __syncthreads();
  s = red[0] + red[1] + red[2] + red[3];
  s2 = red[4] + red[5] + red[6] + red[7];
  float mu = s * (1.f / 1024.f);
  float var = fmaxf(s2 * (1.f / 1024.f) - mu * mu, 0.f);
  float rstd = rsqrtf(var + 1e-12f);
  int col = t * 4;
  float y0 = (x0 - mu) * rstd * g[col + 0] + bta[col + 0];
  float y1 = (x1 - mu) * rstd * g[col + 1] + bta[col + 1];
  float y2 = (x2 - mu) * rstd * g[col + 2] + bta[col + 2];
  float y3 = (x3 - mu) * rstd * g[col + 3] + bta[col + 3];
  if (outb){
    ushort4 o; o.x = f2bf(y0); o.y = f2bf(y1); o.z = f2bf(y2); o.w = f2bf(y3);
    *(ushort4*)(outb + (size_t)row * 1024 + col) = o;
  } else {
    float4 o; o.x = y0; o.y = y1; o.z = y2; o.w = y3;
    *(float4*)(outf + (size_t)row * 1024 + col) = o;
  }
}

extern "C" void kernel_launch(void* const* d_in, const int* in_sizes, int n_in,
                              void* d_out, int out_size, void* d_ws, size_t ws_size,
                              hipStream_t stream){
  const float* enc = (const float*)d_in[0];
  const float* dec = (const float*)d_in[1];
  const int* smask = (const int*)d_in[2];
  const float* q_w  = (const float*)d_in[4];  const float* q_b  = (const float*)d_in[5];
  const float* k_w  = (const float*)d_in[6];  const float* k_b  = (const float*)d_in[7];
  const float* v_w  = (const float*)d_in[8];  const float* v_b  = (const float*)d_in[9];
  const float* sq_w = (const float*)d_in[10]; const float* sq_b = (const float*)d_in[11];
  const float* sk_w = (const float*)d_in[12]; const float* sk_b = (const float*)d_in[13];
  const float* sv_w = (const float*)d_in[14]; const float* sv_b = (const float*)d_in[15];
  const float* dw   = (const float*)d_in[16]; const float* db   = (const float*)d_in[17];
  const float* lng  = (const float*)d_in[18]; const float* lnb  = (const float*)d_in[19];
  ushort* ws = (ushort*)d_ws;
  const size_t MEG = 1024u * 1024u;
  ushort* decb = ws + 0 * MEG;
  ushort* encb = ws + 4 * MEG;
  ushort* Qb   = ws + 8 * MEG;
  ushort* Kb   = ws + 12 * MEG;
  ushort* Vtb  = ws + 20 * MEG;
  ushort* ctx  = ws + 24 * MEG;
  ushort* S1   = ws + 28 * MEG;
  ushort* Wq  = ws + 32 * MEG; ushort* Wk  = ws + 33 * MEG; ushort* Wv  = ws + 34 * MEG;
  ushort* Wsq = ws + 35 * MEG; ushort* Wsk = ws + 36 * MEG; ushort* Wsv = ws + 37 * MEG;
  ushort* Wd  = ws + 38 * MEG;
  const int M = 4096, N = 1024, Kd = 1024;
  cvtk<<<4096, 256, 0, stream>>>(dec, decb, (int)(4 * MEG));
  cvtk<<<4096, 256, 0, stream>>>(enc, encb, (int)(4 * MEG));
  cvtk<<<1024, 256, 0, stream>>>(q_w,  Wq,  (int)MEG);
  cvtk<<<1024, 256, 0, stream>>>(k_w,  Wk,  (int)MEG);
  cvtk<<<1024, 256, 0, stream>>>(v_w,  Wv,  (int)MEG);
  cvtk<<<1024, 256, 0, stream>>>(sq_w, Wsq, (int)MEG);
  cvtk<<<1024, 256, 0, stream>>>(sk_w, Wsk, (int)MEG);
  cvtk<<<1024, 256, 0, stream>>>(sv_w, Wsv, (int)MEG);
  cvtk<<<1024, 256, 0, stream>>>(dw,   Wd,  (int)MEG);
  // ---- self attention ----
  {
    GemmArgs ga;
    ga.A[0] = decb; ga.A[1] = decb; ga.A[2] = decb;
    ga.W[0] = Wq;   ga.W[1] = Wk;   ga.W[2] = Wv;
    ga.bias[0] = q_b; ga.bias[1] = k_b; ga.bias[2] = v_b;
    ga.R[0] = nullptr; ga.R[1] = nullptr; ga.R[2] = nullptr;
    ga.C[0] = Qb;   ga.C[1] = Kb;   ga.C[2] = Vtb;
    ga.mode[0] = 0; ga.mode[1] = 0; ga.mode[2] = 2;
    gemm_bt<<<1536, 256, 0, stream>>>(ga, 3, M, N, Kd);
  }
  attn_kernel<<<512, 256, 0, stream>>>(Qb, Kb, Vtb, ctx, nullptr, 1);
  {
    GemmArgs ga = {};
    ga.A[0] = ctx; ga.W[0] = Wd; ga.bias[0] = db; ga.R[0] = Qb; ga.C[0] = S1; ga.mode[0] = 1;
    gemm_bt<<<512, 256, 0, stream>>>(ga, 1, M, N, Kd);
  }
  ln_kernel<<<4096, 256, 0, stream>>>(S1, lng, lnb, decb, nullptr);
  // ---- cross attention ----
  {
    GemmArgs ga;
    ga.A[0] = decb; ga.A[1] = encb; ga.A[2] = encb;
    ga.W[0] = Wsq;  ga.W[1] = Wsk;  ga.W[2] = Wsv;
    ga.bias[0] = sq_b; ga.bias[1] = sk_b; ga.bias[2] = sv_b;
    ga.R[0] = nullptr; ga.R[1] = nullptr; ga.R[2] = nullptr;
    ga.C[0] = Qb;   ga.C[1] = Kb;   ga.C[2] = Vtb;
    ga.mode[0] = 0; ga.mode[1] = 0; ga.mode[2] = 2;
    gemm_bt<<<1536, 256, 0, stream>>>(ga, 3, M, N, Kd);
  }
  attn_kernel<<<512, 256, 0, stream>>>(Qb, Kb, Vtb, ctx, smask, 0);
  {
    GemmArgs ga = {};
    ga.A[0] = ctx; ga.W[0] = Wd; ga.bias[0] = db; ga.R[0] = Qb; ga.C[0] = S1; ga.mode[0] = 1;
    gemm_bt<<<512, 256, 0, stream>>>(ga, 1, M, N, Kd);
  }
  ln_kernel<<<4096, 256, 0, stream>>>(S1, lng, lnb, nullptr, (float*)d_out);
}

// Round 4
// 225.022 us; speedup vs baseline: 2.3641x; 1.1653x over previous
//
#include <hip/hip_runtime.h>

typedef __attribute__((ext_vector_type(4))) float f32x4;
typedef __attribute__((ext_vector_type(8))) short bf16x8;

#define GVOID const __attribute__((address_space(1))) void
#define LVOID __attribute__((address_space(3))) void

__device__ __forceinline__ float bf2f(ushort u){
  union { float f; unsigned int i; } c; c.i = ((unsigned int)u) << 16; return c.f;
}
__device__ __forceinline__ ushort f2bf(float f){
  union { float f; unsigned int i; } c; c.f = f;
  unsigned int r = (c.i + 0x7FFFu + ((c.i >> 16) & 1u)) >> 16;
  return (ushort)r;
}

// ---------------- fused f32 -> bf16 convert (all 9 tensors, one dispatch) ----------------
struct CvtArgs {
  const float* s[9];
  ushort*      d[9];
  int          blks[9];
};
__global__ __launch_bounds__(256) void cvtk_multi(CvtArgs ca){
  int bid = blockIdx.x;
  int seg = 0, base = 0;
  while (bid - base >= ca.blks[seg]){ base += ca.blks[seg]; ++seg; }
  int i = ((bid - base) * 256 + threadIdx.x) * 4;
  float4 v = *(const float4*)(ca.s[seg] + i);
  ushort4 o;
  o.x = f2bf(v.x); o.y = f2bf(v.y); o.z = f2bf(v.z); o.w = f2bf(v.w);
  *(ushort4*)(ca.d[seg] + i) = o;
}

// ---------------- GEMM args ----------------
struct GemmArgs {
  const ushort* A[3];
  const ushort* W[3];
  const float*  bias[3];
  const ushort* R[3];
  ushort*       C[3];
  int           mode[3];
};

// ---------------- GEMM 128x128 (m97 structure): single-buffered, 2 barriers/K-step ----------------
// 4 waves 2x2, wave tile 64x64 (4x4 fragments). BK=64.
__global__ __launch_bounds__(256,2) void gemm128(GemmArgs ga, int nmat, int N, int K){
  __shared__ ushort As[128 * 64];
  __shared__ ushort Bs[128 * 64];
  const int ntn = N >> 7;
  const int per = ntn * nmat;
  const int x = blockIdx.x & 7, ii = blockIdx.x >> 3;
  const int ipx = gridDim.x >> 3;
  const int gpx = ipx / per;
  const int tm = x * gpx + ii / per;
  const int q = ii % per;
  const int g = q / ntn, tn = q % ntn;
  const ushort* __restrict__ A = ga.A[g];
  const ushort* __restrict__ W = ga.W[g];
  const float*  __restrict__ bias = ga.bias[g];
  const ushort* __restrict__ R = ga.R[g];
  ushort* __restrict__ C = ga.C[g];
  const int mode = ga.mode[g];

  const int t = threadIdx.x, lane = t & 63, wave = t >> 6;
  const int wr = wave >> 1, wc = wave & 1;
  const int l15 = lane & 15, l4 = lane >> 4;
  const int rowBase = tm * 128, colBase = tn * 128;

  f32x4 acc[4][4] = {};
  const int NT = K >> 6;
  for (int tk = 0; tk < NT; ++tk){
    const int k0 = tk * 64;
    __syncthreads();
#pragma unroll
    for (int j = 0; j < 4; ++j){
      int cb = j * 256 + wave * 64 + lane;      // chunk 0..1023
      int row = cb >> 3;
      int kc = (cb & 7) ^ (row & 7);
      const ushort* srcA = A + (size_t)(rowBase + row) * K + k0 + kc * 8;
      __builtin_amdgcn_global_load_lds((GVOID*)srcA, (LVOID*)(As + (size_t)cb * 8), 16, 0, 0);
      const ushort* srcB = W + (size_t)(colBase + row) * K + k0 + kc * 8;
      __builtin_amdgcn_global_load_lds((GVOID*)srcB, (LVOID*)(Bs + (size_t)cb * 8), 16, 0, 0);
    }
    __syncthreads();
#pragma unroll
    for (int kk = 0; kk < 2; ++kk){
      bf16x8 a[4], b[4];
#pragma unroll
      for (int m = 0; m < 4; ++m){
        int row = wr * 64 + m * 16 + l15;
        int ch = row * 8 + ((kk * 4 + l4) ^ (row & 7));
        a[m] = *(const bf16x8*)(As + ch * 8);
      }
#pragma unroll
      for (int n = 0; n < 4; ++n){
        int row = wc * 64 + n * 16 + l15;
        int ch = row * 8 + ((kk * 4 + l4) ^ (row & 7));
        b[n] = *(const bf16x8*)(Bs + ch * 8);
      }
#pragma unroll
      for (int m = 0; m < 4; ++m)
#pragma unroll
      for (int n = 0; n < 4; ++n)
        acc[m][n] = __builtin_amdgcn_mfma_f32_16x16x32_bf16(a[m], b[n], acc[m][n], 0, 0, 0);
    }
  }
  // epilogue
#pragma unroll
  for (int m = 0; m < 4; ++m)
#pragma unroll
  for (int n = 0; n < 4; ++n)
#pragma unroll
  for (int r = 0; r < 4; ++r){
    int row = rowBase + wr * 64 + m * 16 + l4 * 4 + r;
    int col = colBase + wc * 64 + n * 16 + l15;
    float v = acc[m][n][r] + bias[col];
    if (mode == 1) v += bf2f(R[(size_t)row * N + col]);
    if (mode == 2){
      int bb = row >> 10, tt = row & 1023, nh = col >> 6, d = col & 63;
      C[((size_t)((bb * 16 + nh) * 64 + d)) * 1024 + tt] = f2bf(v);
    } else {
      C[(size_t)row * N + col] = f2bf(v);
    }
  }
}

// ---------------- GEMM 128x64 double-buffered (dense projection) ----------------
__global__ __launch_bounds__(256,2) void gemm_bt(GemmArgs ga, int nmat, int M, int N, int K){
  __shared__ ushort As[2][128 * 64];
  __shared__ ushort Bs[2][64 * 64];
  const int nb = gridDim.x;
  const int ntn = N >> 6;
  const int tq_cnt = ntn * nmat;
  const int x = blockIdx.x & 7, ii = blockIdx.x >> 3;
  const int ipx = nb >> 3;
  const int gpx = ipx / tq_cnt;
  const int tm = x * gpx + ii / tq_cnt;
  const int tq = ii % tq_cnt;
  const int g = tq / ntn, tn = tq % ntn;
  const ushort* __restrict__ A = ga.A[g];
  const ushort* __restrict__ W = ga.W[g];
  const float*  __restrict__ bias = ga.bias[g];
  const ushort* __restrict__ R = ga.R[g];
  ushort* __restrict__ C = ga.C[g];
  const int mode = ga.mode[g];

  const int t = threadIdx.x, lane = t & 63, wave = t >> 6;
  const int wr = wave >> 1, wc = wave & 1;
  const int l15 = lane & 15, l4 = lane >> 4;
  const int rowBase = tm * 128, colBase = tn * 64;

  auto stage = [&](int buf, int k0){
#pragma unroll
    for (int j = 0; j < 4; ++j){
      int cb = j * 256 + wave * 64;
      int p = cb + lane;
      int row = p >> 3;
      int kc = (p & 7) ^ (row & 7);
      const ushort* src = A + (size_t)(rowBase + row) * K + k0 + kc * 8;
      __builtin_amdgcn_global_load_lds((GVOID*)src, (LVOID*)(&As[buf][cb * 8]), 16, 0, 0);
    }
#pragma unroll
    for (int j = 0; j < 2; ++j){
      int cb = j * 256 + wave * 64;
      int p = cb + lane;
      int row = p >> 3;
      int kc = (p & 7) ^ (row & 7);
      const ushort* src = W + (size_t)(colBase + row) * K + k0 + kc * 8;
      __builtin_amdgcn_global_load_lds((GVOID*)src, (LVOID*)(&Bs[buf][cb * 8]), 16, 0, 0);
    }
  };

  f32x4 acc[4][2] = {};
  const int NT = K >> 6;
  stage(0, 0);
  __syncthreads();
  for (int tk = 0; tk < NT; ++tk){
    const int cur = tk & 1;
    if (tk + 1 < NT) stage(cur ^ 1, (tk + 1) * 64);
#pragma unroll
    for (int kk = 0; kk < 2; ++kk){
      bf16x8 a[4], b[2];
#pragma unroll
      for (int m = 0; m < 4; ++m){
        int row = wr * 64 + m * 16 + l15;
        int ch = row * 8 + kk * 4 + l4;
        ch ^= (row & 7);
        a[m] = *(const bf16x8*)(&As[cur][ch * 8]);
      }
#pragma unroll
      for (int n = 0; n < 2; ++n){
        int row = wc * 32 + n * 16 + l15;
        int ch = row * 8 + kk * 4 + l4;
        ch ^= (row & 7);
        b[n] = *(const bf16x8*)(&Bs[cur][ch * 8]);
      }
#pragma unroll
      for (int m = 0; m < 4; ++m)
#pragma unroll
      for (int n = 0; n < 2; ++n)
        acc[m][n] = __builtin_amdgcn_mfma_f32_16x16x32_bf16(a[m], b[n], acc[m][n], 0, 0, 0);
    }
    __syncthreads();
  }
#pragma unroll
  for (int m = 0; m < 4; ++m)
#pragma unroll
  for (int n = 0; n < 2; ++n)
#pragma unroll
  for (int r = 0; r < 4; ++r){
    int row = rowBase + wr * 64 + m * 16 + l4 * 4 + r;
    int col = colBase + wc * 32 + n * 16 + l15;
    float v = acc[m][n][r] + bias[col];
    if (mode == 1) v += bf2f(R[(size_t)row * N + col]);
    if (mode == 2){
      int bb = row >> 10, tt = row & 1023, nh = col >> 6, d = col & 63;
      C[((size_t)((bb * 16 + nh) * 64 + d)) * 1024 + tt] = f2bf(v);
    } else {
      C[(size_t)row * N + col] = f2bf(v);
    }
  }
}

// ---------------- fused flash attention v3 ----------------
__global__ __launch_bounds__(256,2) void attn_kernel(const ushort* __restrict__ Q, const ushort* __restrict__ Kv,
    const ushort* __restrict__ Vt, ushort* __restrict__ O, const int* __restrict__ smask, int causal){
  __shared__ ushort Ks[2][64 * 64];
  __shared__ ushort Vs[2][64 * 64];
  __shared__ __align__(16) char Ps[4][4096];
  const int p = blockIdx.x;
  const int x = p & 7, j = p >> 3;
  const int gg = x * 8 + (j & 7);
  const int b = gg >> 4, head = gg & 15;
  const int c3 = (j >> 3) & 3, rr = j >> 5;
  const int qt = causal ? (rr ? (7 - c3) : c3) : (j >> 3);
  const int t = threadIdx.x, lane = t & 63, wave = t >> 6;
  const int l15 = lane & 15, l4 = lane >> 4;
  const int qr0 = qt * 128 + wave * 32;
  const int sw = (l15 & 7) << 3;

  bf16x8 aq[2][2];
#pragma unroll
  for (int m = 0; m < 2; ++m)
#pragma unroll
  for (int kk = 0; kk < 2; ++kk)
    aq[m][kk] = *(const bf16x8*)(Q + (size_t)(b * 1024 + qr0 + m * 16 + l15) * 1024 + head * 64 + kk * 32 + l4 * 8);

  f32x4 cacc[2][4] = {};
  float mrow[2] = {-1e30f, -1e30f}, lrow[2] = {0.f, 0.f};

  auto stage = [&](int buf, int k0){
#pragma unroll
    for (int jj = 0; jj < 2; ++jj){
      int cb = jj * 256 + wave * 64;
      int pp = cb + lane;
      int row = pp >> 3;
      int kc = (pp & 7) ^ (row & 7);
      const ushort* src = Kv + (size_t)(b * 1024 + k0 + row) * 1024 + head * 64 + kc * 8;
      __builtin_amdgcn_global_load_lds((GVOID*)src, (LVOID*)(&Ks[buf][cb * 8]), 16, 0, 0);
    }
#pragma unroll
    for (int jj = 0; jj < 2; ++jj){
      int cb = jj * 256 + wave * 64;
      int pp = cb + lane;
      int row = pp >> 3;
      int kc = (pp & 7) ^ (row & 7);
      const ushort* src = Vt + (size_t)((b * 16 + head) * 64 + row) * 1024 + k0 + kc * 8;
      __builtin_amdgcn_global_load_lds((GVOID*)src, (LVOID*)(&Vs[buf][cb * 8]), 16, 0, 0);
    }
  };

  const int nkt = causal ? (2 * qt + 2) : 16;
  stage(0, 0);
  __syncthreads();
  char* Pb = &Ps[wave][0];
  for (int kt = 0; kt < nkt; ++kt){
    const int cur = kt & 1;
    const int k0 = kt * 64;
    if (kt + 1 < nkt) stage(cur ^ 1, (kt + 1) * 64);
    const ushort* Kb_ = &Ks[cur][0];
    const ushort* Vb_ = &Vs[cur][0];
    f32x4 st[2][4] = {};
#pragma unroll
    for (int kk = 0; kk < 2; ++kk){
      bf16x8 ak[4];
#pragma unroll
      for (int n = 0; n < 4; ++n){
        int row = n * 16 + l15;
        int ch = row * 8 + ((kk * 4 + l4) ^ (row & 7));
        ak[n] = *(const bf16x8*)(Kb_ + ch * 8);
      }
#pragma unroll
      for (int m = 0; m < 2; ++m)
#pragma unroll
      for (int n = 0; n < 4; ++n)
        st[m][n] = __builtin_amdgcn_mfma_f32_16x16x32_bf16(ak[n], aq[m][kk], st[m][n], 0, 0, 0);
    }
    if (causal && k0 + 63 > qr0){
#pragma unroll
      for (int m = 0; m < 2; ++m)
#pragma unroll
      for (int n = 0; n < 4; ++n)
#pragma unroll
      for (int r = 0; r < 4; ++r)
        if (k0 + n * 16 + l4 * 4 + r > qr0 + m * 16 + l15) st[m][n][r] = -1e6f;
    }
    if (smask){
#pragma unroll
      for (int n = 0; n < 4; ++n)
#pragma unroll
      for (int r = 0; r < 4; ++r){
        int mv = smask[b * 1024 + k0 + n * 16 + l4 * 4 + r];
        if (mv == 0){ st[0][n][r] = -1e6f; st[1][n][r] = -1e6f; }
      }
    }
    float scal[2];
#pragma unroll
    for (int m = 0; m < 2; ++m){
      float mx = st[m][0][0];
#pragma unroll
      for (int n = 0; n < 4; ++n)
#pragma unroll
      for (int r = 0; r < 4; ++r) mx = fmaxf(mx, st[m][n][r]);
      mx = fmaxf(mx, __shfl_xor(mx, 16));
      mx = fmaxf(mx, __shfl_xor(mx, 32));
      float mn = fmaxf(mrow[m], mx);
      scal[m] = __expf(mrow[m] - mn);
      mrow[m] = mn;
      float ps = 0.f;
#pragma unroll
      for (int n = 0; n < 4; ++n)
#pragma unroll
      for (int r = 0; r < 4; ++r){
        float pv = __expf(st[m][n][r] - mn);
        st[m][n][r] = pv;
        ps += pv;
      }
      ps += __shfl_xor(ps, 16);
      ps += __shfl_xor(ps, 32);
      lrow[m] = lrow[m] * scal[m] + ps;
    }
#pragma unroll
    for (int m = 0; m < 2; ++m)
#pragma unroll
    for (int r = 0; r < 4; ++r){
      float sb = __shfl(scal[m], l4 * 4 + r);
#pragma unroll
      for (int nd = 0; nd < 4; ++nd) cacc[m][nd][r] *= sb;
    }
#pragma unroll
    for (int m = 0; m < 2; ++m)
#pragma unroll
    for (int n = 0; n < 4; ++n){
      unsigned lo = (unsigned)f2bf(st[m][n][0]) | ((unsigned)f2bf(st[m][n][1]) << 16);
      unsigned hi = (unsigned)f2bf(st[m][n][2]) | ((unsigned)f2bf(st[m][n][3]) << 16);
      unsigned long long pk = (unsigned long long)lo | ((unsigned long long)hi << 32);
      *(unsigned long long*)(Pb + m * 2048 + l15 * 128 + ((n * 32 + l4 * 8) ^ sw)) = pk;
    }
#pragma unroll
    for (int ks = 0; ks < 2; ++ks){
      bf16x8 bv[4];
#pragma unroll
      for (int nd = 0; nd < 4; ++nd){
        int row = nd * 16 + l15;
        int ch = row * 8 + ((ks * 4 + l4) ^ (row & 7));
        bv[nd] = *(const bf16x8*)(Vb_ + ch * 8);
      }
#pragma unroll
      for (int m = 0; m < 2; ++m){
        int base = m * 2048 + l15 * 128;
        int o = ks * 64 + l4 * 16;
        union { bf16x8 v; unsigned long long u[2]; } pa;
        pa.u[0] = *(const unsigned long long*)(Pb + base + ((o    ) ^ sw));
        pa.u[1] = *(const unsigned long long*)(Pb + base + ((o + 8) ^ sw));
#pragma unroll
        for (int nd = 0; nd < 4; ++nd)
          cacc[m][nd] = __builtin_amdgcn_mfma_f32_16x16x32_bf16(pa.v, bv[nd], cacc[m][nd], 0, 0, 0);
      }
    }
    __syncthreads();
  }
#pragma unroll
  for (int m = 0; m < 2; ++m)
#pragma unroll
  for (int r = 0; r < 4; ++r){
    float lb = __shfl(lrow[m], l4 * 4 + r);
    float inv = 1.f / lb;
    int row = qr0 + m * 16 + l4 * 4 + r;
#pragma unroll
    for (int nd = 0; nd < 4; ++nd){
      int col = head * 64 + nd * 16 + l15;
      O[(size_t)(b * 1024 + row) * 1024 + col] = f2bf(cacc[m][nd][r] * inv);
    }
  }
}

// ---------------- LayerNorm over H=1024 ----------------
__global__ __launch_bounds__(256) void ln_kernel(const ushort* __restrict__ X, const float* __restrict__ g,
    const float* __restrict__ bta, ushort* __restrict__ outb, float* __restrict__ outf){
  const int row = blockIdx.x, t = threadIdx.x;
  const ushort* xr = X + (size_t)row * 1024;
  ushort4 u = *(const ushort4*)(xr + t * 4);
  float x0 = bf2f(u.x), x1 = bf2f(u.y), x2 = bf2f(u.z), x3 = bf2f(u.w);
  float s = x0 + x1 + x2 + x3;
  float s2 = x0 * x0 + x1 * x1 + x2 * x2 + x3 * x3;
#pragma unroll
  for (int d = 1; d < 64; d <<= 1){ s += __shfl_xor(s, d); s2 += __shfl_xor(s2, d); }
  __shared__ float red[8];
  const int lane = t & 63, wave = t >> 6;
  if (lane == 0){ red[wave] = s; red[4 + wave] = s2; }
  __syncthreads();
  s = red[0] + red[1] + red[2] + red[3];
  s2 = red[4] + red[5] + red[6] + red[7];
  float mu = s * (1.f / 1024.f);
  float var = fmaxf(s2 * (1.f / 1024.f) - mu * mu, 0.f);
  float rstd = rsqrtf(var + 1e-12f);
  int col = t * 4;
  float y0 = (x0 - mu) * rstd * g[col + 0] + bta[col + 0];
  float y1 = (x1 - mu) * rstd * g[col + 1] + bta[col + 1];
  float y2 = (x2 - mu) * rstd * g[col + 2] + bta[col + 2];
  float y3 = (x3 - mu) * rstd * g[col + 3] + bta[col + 3];
  if (outb){
    ushort4 o; o.x = f2bf(y0); o.y = f2bf(y1); o.z = f2bf(y2); o.w = f2bf(y3);
    *(ushort4*)(outb + (size_t)row * 1024 + col) = o;
  } else {
    float4 o; o.x = y0; o.y = y1; o.z = y2; o.w = y3;
    *(float4*)(outf + (size_t)row * 1024 + col) = o;
  }
}

extern "C" void kernel_launch(void* const* d_in, const int* in_sizes, int n_in,
                              void* d_out, int out_size, void* d_ws, size_t ws_size,
                              hipStream_t stream){
  const float* enc = (const float*)d_in[0];
  const float* dec = (const float*)d_in[1];
  const int* smask = (const int*)d_in[2];
  const float* q_w  = (const float*)d_in[4];  const float* q_b  = (const float*)d_in[5];
  const float* k_w  = (const float*)d_in[6];  const float* k_b  = (const float*)d_in[7];
  const float* v_w  = (const float*)d_in[8];  const float* v_b  = (const float*)d_in[9];
  const float* sq_w = (const float*)d_in[10]; const float* sq_b = (const float*)d_in[11];
  const float* sk_w = (const float*)d_in[12]; const float* sk_b = (const float*)d_in[13];
  const float* sv_w = (const float*)d_in[14]; const float* sv_b = (const float*)d_in[15];
  const float* dw   = (const float*)d_in[16]; const float* db   = (const float*)d_in[17];
  const float* lng  = (const float*)d_in[18]; const float* lnb  = (const float*)d_in[19];
  ushort* ws = (ushort*)d_ws;
  const size_t MEG = 1024u * 1024u;
  ushort* decb = ws + 0 * MEG;
  ushort* encb = ws + 4 * MEG;
  ushort* Qb   = ws + 8 * MEG;
  ushort* Kb   = ws + 12 * MEG;
  ushort* Vtb  = ws + 20 * MEG;
  ushort* ctx  = ws + 24 * MEG;
  ushort* S1   = ws + 28 * MEG;
  ushort* Wq  = ws + 32 * MEG; ushort* Wk  = ws + 33 * MEG; ushort* Wv  = ws + 34 * MEG;
  ushort* Wsq = ws + 35 * MEG; ushort* Wsk = ws + 36 * MEG; ushort* Wsv = ws + 37 * MEG;
  ushort* Wd  = ws + 38 * MEG;
  const int M = 4096, N = 1024, Kd = 1024;
  // single fused convert dispatch
  {
    CvtArgs ca;
    ca.s[0] = dec;  ca.d[0] = decb; ca.blks[0] = 4096;
    ca.s[1] = enc;  ca.d[1] = encb; ca.blks[1] = 4096;
    ca.s[2] = q_w;  ca.d[2] = Wq;   ca.blks[2] = 1024;
    ca.s[3] = k_w;  ca.d[3] = Wk;   ca.blks[3] = 1024;
    ca.s[4] = v_w;  ca.d[4] = Wv;   ca.blks[4] = 1024;
    ca.s[5] = sq_w; ca.d[5] = Wsq;  ca.blks[5] = 1024;
    ca.s[6] = sk_w; ca.d[6] = Wsk;  ca.blks[6] = 1024;
    ca.s[7] = sv_w; ca.d[7] = Wsv;  ca.blks[7] = 1024;
    ca.s[8] = dw;   ca.d[8] = Wd;   ca.blks[8] = 1024;
    cvtk_multi<<<15360, 256, 0, stream>>>(ca);
  }
  // ---- self attention ----
  {
    GemmArgs ga;
    ga.A[0] = decb; ga.A[1] = decb; ga.A[2] = decb;
    ga.W[0] = Wq;   ga.W[1] = Wk;   ga.W[2] = Wv;
    ga.bias[0] = q_b; ga.bias[1] = k_b; ga.bias[2] = v_b;
    ga.R[0] = nullptr; ga.R[1] = nullptr; ga.R[2] = nullptr;
    ga.C[0] = Qb;   ga.C[1] = Kb;   ga.C[2] = Vtb;
    ga.mode[0] = 0; ga.mode[1] = 0; ga.mode[2] = 2;
    gemm128<<<768, 256, 0, stream>>>(ga, 3, N, Kd);
  }
  attn_kernel<<<512, 256, 0, stream>>>(Qb, Kb, Vtb, ctx, nullptr, 1);
  {
    GemmArgs ga = {};
    ga.A[0] = ctx; ga.W[0] = Wd; ga.bias[0] = db; ga.R[0] = Qb; ga.C[0] = S1; ga.mode[0] = 1;
    gemm_bt<<<512, 256, 0, stream>>>(ga, 1, M, N, Kd);
  }
  ln_kernel<<<4096, 256, 0, stream>>>(S1, lng, lnb, decb, nullptr);
  // ---- cross attention ----
  {
    GemmArgs ga;
    ga.A[0] = decb; ga.A[1] = encb; ga.A[2] = encb;
    ga.W[0] = Wsq;  ga.W[1] = Wsk;  ga.W[2] = Wsv;
    ga.bias[0] = sq_b; ga.bias[1] = sk_b; ga.bias[2] = sv_b;
    ga.R[0] = nullptr; ga.R[1] = nullptr; ga.R[2] = nullptr;
    ga.C[0] = Qb;   ga.C[1] = Kb;   ga.C[2] = Vtb;
    ga.mode[0] = 0; ga.mode[1] = 0; ga.mode[2] = 2;
    gemm128<<<768, 256, 0, stream>>>(ga, 3, N, Kd);
  }
  attn_kernel<<<512, 256, 0, stream>>>(Qb, Kb, Vtb, ctx, smask, 0);
  {
    GemmArgs ga = {};
    ga.A[0] = ctx; ga.W[0] = Wd; ga.bias[0] = db; ga.R[0] = Qb; ga.C[0] = S1; ga.mode[0] = 1;
    gemm_bt<<<512, 256, 0, stream>>>(ga, 1, M, N, Kd);
  }
  ln_kernel<<<4096, 256, 0, stream>>>(S1, lng, lnb, nullptr, (float*)d_out);
}

// Round 5
// 212.984 us; speedup vs baseline: 2.4977x; 1.0565x over previous
//
#include <hip/hip_runtime.h>

typedef __attribute__((ext_vector_type(4))) float f32x4;
typedef __attribute__((ext_vector_type(8))) short bf16x8;

#define GVOID const __attribute__((address_space(1))) void
#define LVOID __attribute__((address_space(3))) void

#define LOG2E 1.44269504f
#define LN2   0.69314718f

__device__ __forceinline__ float bf2f(ushort u){
  union { float f; unsigned int i; } c; c.i = ((unsigned int)u) << 16; return c.f;
}
__device__ __forceinline__ ushort f2bf(float f){
  union { float f; unsigned int i; } c; c.f = f;
  unsigned int r = (c.i + 0x7FFFu + ((c.i >> 16) & 1u)) >> 16;
  return (ushort)r;
}

// ---------------- fused f32 -> bf16 convert (all 9 tensors, one dispatch) ----------------
struct CvtArgs {
  const float* s[9];
  ushort*      d[9];
  int          blks[9];
};
__global__ __launch_bounds__(256) void cvtk_multi(CvtArgs ca){
  int bid = blockIdx.x;
  int seg = 0, base = 0;
  while (bid - base >= ca.blks[seg]){ base += ca.blks[seg]; ++seg; }
  int i = ((bid - base) * 256 + threadIdx.x) * 4;
  float4 v = *(const float4*)(ca.s[seg] + i);
  ushort4 o;
  o.x = f2bf(v.x); o.y = f2bf(v.y); o.z = f2bf(v.z); o.w = f2bf(v.w);
  *(ushort4*)(ca.d[seg] + i) = o;
}

// ---------------- GEMM args ----------------
struct GemmArgs {
  const ushort* A[3];
  const ushort* W[3];
  const float*  bias[3];
  const ushort* R[3];
  ushort*       C[3];
  int           mode[3];
  float         scale[3];
};

// ---------------- GEMM 128x128 (m97 structure): single-buffered, 2 barriers/K-step ----------------
__global__ __launch_bounds__(256,2) void gemm128(GemmArgs ga, int nmat, int N, int K){
  __shared__ ushort As[128 * 64];
  __shared__ ushort Bs[128 * 64];
  const int ntn = N >> 7;
  const int per = ntn * nmat;
  const int x = blockIdx.x & 7, ii = blockIdx.x >> 3;
  const int ipx = gridDim.x >> 3;
  const int gpx = ipx / per;
  const int tm = x * gpx + ii / per;
  const int q = ii % per;
  const int g = q / ntn, tn = q % ntn;
  const ushort* __restrict__ A = ga.A[g];
  const ushort* __restrict__ W = ga.W[g];
  const float*  __restrict__ bias = ga.bias[g];
  ushort* __restrict__ C = ga.C[g];
  const int mode = ga.mode[g];
  const float scale = ga.scale[g];

  const int t = threadIdx.x, lane = t & 63, wave = t >> 6;
  const int wr = wave >> 1, wc = wave & 1;
  const int l15 = lane & 15, l4 = lane >> 4;
  const int rowBase = tm * 128, colBase = tn * 128;

  f32x4 acc[4][4] = {};
  const int NT = K >> 6;
  for (int tk = 0; tk < NT; ++tk){
    const int k0 = tk * 64;
    __syncthreads();
#pragma unroll
    for (int j = 0; j < 4; ++j){
      int cb = j * 256 + wave * 64 + lane;
      int row = cb >> 3;
      int kc = (cb & 7) ^ (row & 7);
      const ushort* srcA = A + (size_t)(rowBase + row) * K + k0 + kc * 8;
      __builtin_amdgcn_global_load_lds((GVOID*)srcA, (LVOID*)(As + (size_t)cb * 8), 16, 0, 0);
      const ushort* srcB = W + (size_t)(colBase + row) * K + k0 + kc * 8;
      __builtin_amdgcn_global_load_lds((GVOID*)srcB, (LVOID*)(Bs + (size_t)cb * 8), 16, 0, 0);
    }
    __syncthreads();
#pragma unroll
    for (int kk = 0; kk < 2; ++kk){
      bf16x8 a[4], b[4];
#pragma unroll
      for (int m = 0; m < 4; ++m){
        int row = wr * 64 + m * 16 + l15;
        int ch = row * 8 + ((kk * 4 + l4) ^ (row & 7));
        a[m] = *(const bf16x8*)(As + ch * 8);
      }
#pragma unroll
      for (int n = 0; n < 4; ++n){
        int row = wc * 64 + n * 16 + l15;
        int ch = row * 8 + ((kk * 4 + l4) ^ (row & 7));
        b[n] = *(const bf16x8*)(Bs + ch * 8);
      }
#pragma unroll
      for (int m = 0; m < 4; ++m)
#pragma unroll
      for (int n = 0; n < 4; ++n)
        acc[m][n] = __builtin_amdgcn_mfma_f32_16x16x32_bf16(a[m], b[n], acc[m][n], 0, 0, 0);
    }
  }
#pragma unroll
  for (int m = 0; m < 4; ++m)
#pragma unroll
  for (int n = 0; n < 4; ++n)
#pragma unroll
  for (int r = 0; r < 4; ++r){
    int row = rowBase + wr * 64 + m * 16 + l4 * 4 + r;
    int col = colBase + wc * 64 + n * 16 + l15;
    float v = (acc[m][n][r] + bias[col]) * scale;
    if (mode == 2){
      int bb = row >> 10, tt = row & 1023, nh = col >> 6, d = col & 63;
      C[((size_t)((bb * 16 + nh) * 64 + d)) * 1024 + tt] = f2bf(v);
    } else {
      C[(size_t)row * N + col] = f2bf(v);
    }
  }
}

// ---------------- GEMM 128x64 double-buffered (dense projection, +unscaled residual) ----------------
__global__ __launch_bounds__(256,2) void gemm_bt(GemmArgs ga, int nmat, int M, int N, int K){
  __shared__ ushort As[2][128 * 64];
  __shared__ ushort Bs[2][64 * 64];
  const int nb = gridDim.x;
  const int ntn = N >> 6;
  const int tq_cnt = ntn * nmat;
  const int x = blockIdx.x & 7, ii = blockIdx.x >> 3;
  const int ipx = nb >> 3;
  const int gpx = ipx / tq_cnt;
  const int tm = x * gpx + ii / tq_cnt;
  const int tq = ii % tq_cnt;
  const int g = tq / ntn, tn = tq % ntn;
  const ushort* __restrict__ A = ga.A[g];
  const ushort* __restrict__ W = ga.W[g];
  const float*  __restrict__ bias = ga.bias[g];
  const ushort* __restrict__ R = ga.R[g];
  ushort* __restrict__ C = ga.C[g];
  const int mode = ga.mode[g];

  const int t = threadIdx.x, lane = t & 63, wave = t >> 6;
  const int wr = wave >> 1, wc = wave & 1;
  const int l15 = lane & 15, l4 = lane >> 4;
  const int rowBase = tm * 128, colBase = tn * 64;

  auto stage = [&](int buf, int k0){
#pragma unroll
    for (int j = 0; j < 4; ++j){
      int cb = j * 256 + wave * 64;
      int p = cb + lane;
      int row = p >> 3;
      int kc = (p & 7) ^ (row & 7);
      const ushort* src = A + (size_t)(rowBase + row) * K + k0 + kc * 8;
      __builtin_amdgcn_global_load_lds((GVOID*)src, (LVOID*)(&As[buf][cb * 8]), 16, 0, 0);
    }
#pragma unroll
    for (int j = 0; j < 2; ++j){
      int cb = j * 256 + wave * 64;
      int p = cb + lane;
      int row = p >> 3;
      int kc = (p & 7) ^ (row & 7);
      const ushort* src = W + (size_t)(colBase + row) * K + k0 + kc * 8;
      __builtin_amdgcn_global_load_lds((GVOID*)src, (LVOID*)(&Bs[buf][cb * 8]), 16, 0, 0);
    }
  };

  f32x4 acc[4][2] = {};
  const int NT = K >> 6;
  stage(0, 0);
  __syncthreads();
  for (int tk = 0; tk < NT; ++tk){
    const int cur = tk & 1;
    if (tk + 1 < NT) stage(cur ^ 1, (tk + 1) * 64);
#pragma unroll
    for (int kk = 0; kk < 2; ++kk){
      bf16x8 a[4], b[2];
#pragma unroll
      for (int m = 0; m < 4; ++m){
        int row = wr * 64 + m * 16 + l15;
        int ch = row * 8 + kk * 4 + l4;
        ch ^= (row & 7);
        a[m] = *(const bf16x8*)(&As[cur][ch * 8]);
      }
#pragma unroll
      for (int n = 0; n < 2; ++n){
        int row = wc * 32 + n * 16 + l15;
        int ch = row * 8 + kk * 4 + l4;
        ch ^= (row & 7);
        b[n] = *(const bf16x8*)(&Bs[cur][ch * 8]);
      }
#pragma unroll
      for (int m = 0; m < 4; ++m)
#pragma unroll
      for (int n = 0; n < 2; ++n)
        acc[m][n] = __builtin_amdgcn_mfma_f32_16x16x32_bf16(a[m], b[n], acc[m][n], 0, 0, 0);
    }
    __syncthreads();
  }
#pragma unroll
  for (int m = 0; m < 4; ++m)
#pragma unroll
  for (int n = 0; n < 2; ++n)
#pragma unroll
  for (int r = 0; r < 4; ++r){
    int row = rowBase + wr * 64 + m * 16 + l4 * 4 + r;
    int col = colBase + wc * 32 + n * 16 + l15;
    float v = acc[m][n][r] + bias[col];
    if (mode == 1) v += bf2f(R[(size_t)row * N + col]) * LN2;   // residual Q was stored pre-scaled by LOG2E
    C[(size_t)row * N + col] = f2bf(v);
  }
}

// ---------------- fused flash attention v4 ----------------
// 1024 blocks (b, head, 16 q-tiles of 64), 4 waves x 16 q-rows, 4 blocks/CU.
// Swapped QK^T; Q pre-scaled by LOG2E so softmax uses exp2 directly.
__global__ __launch_bounds__(256,4) void attn_kernel(const ushort* __restrict__ Q, const ushort* __restrict__ Kv,
    const ushort* __restrict__ Vt, ushort* __restrict__ O, const int* __restrict__ smask, int causal){
  __shared__ ushort Ks[2][64 * 64];
  __shared__ ushort Vs[2][64 * 64];
  __shared__ __align__(16) char Ps[4][2048];
  const int p = blockIdx.x;
  const int x = p & 7, j = p >> 3;          // XCD, local 0..127
  const int gg = x * 8 + (j & 7);           // (b,head), co-located per XCD
  const int b = gg >> 4, head = gg & 15;
  const int rr = j >> 3;                    // 0..15
  int qt;
  if (causal){
    int lo = rr & 3, hi = rr >> 2;          // stride-4 class balance: {2lo,2lo+1,15-2lo,14-2lo}
    qt = (hi == 0) ? lo * 2 : (hi == 1) ? lo * 2 + 1 : (hi == 2) ? 15 - lo * 2 : 14 - lo * 2;
  } else qt = rr;
  const int t = threadIdx.x, lane = t & 63, wave = t >> 6;
  const int l15 = lane & 15, l4 = lane >> 4;
  const int qr0 = qt * 64 + wave * 16;
  const int sw = (l15 & 7) << 3;

  bf16x8 aq[2];
#pragma unroll
  for (int kk = 0; kk < 2; ++kk)
    aq[kk] = *(const bf16x8*)(Q + (size_t)(b * 1024 + qr0 + l15) * 1024 + head * 64 + kk * 32 + l4 * 8);

  f32x4 cacc[4] = {};
  float mrow = -1e30f, lrow = 0.f;

  auto stage = [&](int buf, int k0){
#pragma unroll
    for (int jj = 0; jj < 2; ++jj){
      int cb = jj * 256 + wave * 64;
      int pp = cb + lane;
      int row = pp >> 3;
      int kc = (pp & 7) ^ (row & 7);
      const ushort* src = Kv + (size_t)(b * 1024 + k0 + row) * 1024 + head * 64 + kc * 8;
      __builtin_amdgcn_global_load_lds((GVOID*)src, (LVOID*)(&Ks[buf][cb * 8]), 16, 0, 0);
    }
#pragma unroll
    for (int jj = 0; jj < 2; ++jj){
      int cb = jj * 256 + wave * 64;
      int pp = cb + lane;
      int row = pp >> 3;
      int kc = (pp & 7) ^ (row & 7);
      const ushort* src = Vt + (size_t)((b * 16 + head) * 64 + row) * 1024 + k0 + kc * 8;
      __builtin_amdgcn_global_load_lds((GVOID*)src, (LVOID*)(&Vs[buf][cb * 8]), 16, 0, 0);
    }
  };

  const int nkt = causal ? (qt + 1) : 16;
  stage(0, 0);
  __syncthreads();
  char* Pb = &Ps[wave][0];
  for (int kt = 0; kt < nkt; ++kt){
    const int cur = kt & 1;
    const int k0 = kt * 64;
    if (kt + 1 < nkt) stage(cur ^ 1, (kt + 1) * 64);
    const ushort* Kb_ = &Ks[cur][0];
    const ushort* Vb_ = &Vs[cur][0];
    // S^T = K Q^T : rows k (n*16 + l4*4 + r), cols q (l15). Logits already x LOG2E.
    f32x4 st[4] = {};
#pragma unroll
    for (int kk = 0; kk < 2; ++kk){
      bf16x8 ak[4];
#pragma unroll
      for (int n = 0; n < 4; ++n){
        int row = n * 16 + l15;
        int ch = row * 8 + ((kk * 4 + l4) ^ (row & 7));
        ak[n] = *(const bf16x8*)(Kb_ + ch * 8);
      }
#pragma unroll
      for (int n = 0; n < 4; ++n)
        st[n] = __builtin_amdgcn_mfma_f32_16x16x32_bf16(ak[n], aq[kk], st[n], 0, 0, 0);
    }
    if (causal && k0 + 63 > qr0){
#pragma unroll
      for (int n = 0; n < 4; ++n)
#pragma unroll
      for (int r = 0; r < 4; ++r)
        if (k0 + n * 16 + l4 * 4 + r > qr0 + l15) st[n][r] = -1.5e6f;
    }
    if (smask){
#pragma unroll
      for (int n = 0; n < 4; ++n)
#pragma unroll
      for (int r = 0; r < 4; ++r){
        int mv = smask[b * 1024 + k0 + n * 16 + l4 * 4 + r];
        if (mv == 0) st[n][r] = -1.5e6f;
      }
    }
    // online softmax in log2 domain (lane owns q = l15; reduce over l4 groups)
    float mx = st[0][0];
#pragma unroll
    for (int n = 0; n < 4; ++n)
#pragma unroll
    for (int r = 0; r < 4; ++r) mx = fmaxf(mx, st[n][r]);
    mx = fmaxf(mx, __shfl_xor(mx, 16));
    mx = fmaxf(mx, __shfl_xor(mx, 32));
    float mn = fmaxf(mrow, mx);
    float scal = __builtin_amdgcn_exp2f(mrow - mn);
    mrow = mn;
    float ps = 0.f;
#pragma unroll
    for (int n = 0; n < 4; ++n)
#pragma unroll
    for (int r = 0; r < 4; ++r){
      float pv = __builtin_amdgcn_exp2f(st[n][r] - mn);
      st[n][r] = pv;
      ps += pv;
    }
    ps += __shfl_xor(ps, 16);
    ps += __shfl_xor(ps, 32);
    lrow = lrow * scal + ps;
    // rescale accumulator (cacc row-domain q = l4*4 + r)
#pragma unroll
    for (int r = 0; r < 4; ++r){
      float sb = __shfl(scal, l4 * 4 + r);
#pragma unroll
      for (int nd = 0; nd < 4; ++nd) cacc[nd][r] *= sb;
    }
    // P -> bf16 via v_cvt_pk, vectorized b64 swizzled store
#pragma unroll
    for (int n = 0; n < 4; ++n){
      unsigned lo_, hi_;
      asm("v_cvt_pk_bf16_f32 %0, %1, %2" : "=v"(lo_) : "v"(st[n][0]), "v"(st[n][1]));
      asm("v_cvt_pk_bf16_f32 %0, %1, %2" : "=v"(hi_) : "v"(st[n][2]), "v"(st[n][3]));
      unsigned long long pk = (unsigned long long)lo_ | ((unsigned long long)hi_ << 32);
      *(unsigned long long*)(Pb + l15 * 128 + ((n * 32 + l4 * 8) ^ sw)) = pk;
    }
    // PV
#pragma unroll
    for (int ks = 0; ks < 2; ++ks){
      bf16x8 bv[4];
#pragma unroll
      for (int nd = 0; nd < 4; ++nd){
        int row = nd * 16 + l15;
        int ch = row * 8 + ((ks * 4 + l4) ^ (row & 7));
        bv[nd] = *(const bf16x8*)(Vb_ + ch * 8);
      }
      int base = l15 * 128;
      int o = ks * 64 + l4 * 16;
      union { bf16x8 v; unsigned long long u[2]; } pa;
      pa.u[0] = *(const unsigned long long*)(Pb + base + ((o    ) ^ sw));
      pa.u[1] = *(const unsigned long long*)(Pb + base + ((o + 8) ^ sw));
#pragma unroll
      for (int nd = 0; nd < 4; ++nd)
        cacc[nd] = __builtin_amdgcn_mfma_f32_16x16x32_bf16(pa.v, bv[nd], cacc[nd], 0, 0, 0);
    }
    __syncthreads();
  }
  // epilogue
#pragma unroll
  for (int r = 0; r < 4; ++r){
    float lb = __shfl(lrow, l4 * 4 + r);
    float inv = 1.f / lb;
    int row = qr0 + l4 * 4 + r;
#pragma unroll
    for (int nd = 0; nd < 4; ++nd){
      int col = head * 64 + nd * 16 + l15;
      O[(size_t)(b * 1024 + row) * 1024 + col] = f2bf(cacc[nd][r] * inv);
    }
  }
}

// ---------------- LayerNorm over H=1024 ----------------
__global__ __launch_bounds__(256) void ln_kernel(const ushort* __restrict__ X, const float* __restrict__ g,
    const float* __restrict__ bta, ushort* __restrict__ outb, float* __restrict__ outf){
  const int row = blockIdx.x, t = threadIdx.x;
  const ushort* xr = X + (size_t)row * 1024;
  ushort4 u = *(const ushort4*)(xr + t * 4);
  float x0 = bf2f(u.x), x1 = bf2f(u.y), x2 = bf2f(u.z), x3 = bf2f(u.w);
  float s = x0 + x1 + x2 + x3;
  float s2 = x0 * x0 + x1 * x1 + x2 * x2 + x3 * x3;
#pragma unroll
  for (int d = 1; d < 64; d <<= 1){ s += __shfl_xor(s, d); s2 += __shfl_xor(s2, d); }
  __shared__ float red[8];
  const int lane = t & 63, wave = t >> 6;
  if (lane == 0){ red[wave] = s; red[4 + wave] = s2; }
  __syncthreads();
  s = red[0] + red[1] + red[2] + red[3];
  s2 = red[4] + red[5] + red[6] + red[7];
  float mu = s * (1.f / 1024.f);
  float var = fmaxf(s2 * (1.f / 1024.f) - mu * mu, 0.f);
  float rstd = rsqrtf(var + 1e-12f);
  int col = t * 4;
  float y0 = (x0 - mu) * rstd * g[col + 0] + bta[col + 0];
  float y1 = (x1 - mu) * rstd * g[col + 1] + bta[col + 1];
  float y2 = (x2 - mu) * rstd * g[col + 2] + bta[col + 2];
  float y3 = (x3 - mu) * rstd * g[col + 3] + bta[col + 3];
  if (outb){
    ushort4 o; o.x = f2bf(y0); o.y = f2bf(y1); o.z = f2bf(y2); o.w = f2bf(y3);
    *(ushort4*)(outb + (size_t)row * 1024 + col) = o;
  } else {
    float4 o; o.x = y0; o.y = y1; o.z = y2; o.w = y3;
    *(float4*)(outf + (size_t)row * 1024 + col) = o;
  }
}

extern "C" void kernel_launch(void* const* d_in, const int* in_sizes, int n_in,
                              void* d_out, int out_size, void* d_ws, size_t ws_size,
                              hipStream_t stream){
  const float* enc = (const float*)d_in[0];
  const float* dec = (const float*)d_in[1];
  const int* smask = (const int*)d_in[2];
  const float* q_w  = (const float*)d_in[4];  const float* q_b  = (const float*)d_in[5];
  const float* k_w  = (const float*)d_in[6];  const float* k_b  = (const float*)d_in[7];
  const float* v_w  = (const float*)d_in[8];  const float* v_b  = (const float*)d_in[9];
  const float* sq_w = (const float*)d_in[10]; const float* sq_b = (const float*)d_in[11];
  const float* sk_w = (const float*)d_in[12]; const float* sk_b = (const float*)d_in[13];
  const float* sv_w = (const float*)d_in[14]; const float* sv_b = (const float*)d_in[15];
  const float* dw   = (const float*)d_in[16]; const float* db   = (const float*)d_in[17];
  const float* lng  = (const float*)d_in[18]; const float* lnb  = (const float*)d_in[19];
  ushort* ws = (ushort*)d_ws;
  const size_t MEG = 1024u * 1024u;
  ushort* decb = ws + 0 * MEG;
  ushort* encb = ws + 4 * MEG;
  ushort* Qb   = ws + 8 * MEG;
  ushort* Kb   = ws + 12 * MEG;
  ushort* Vtb  = ws + 20 * MEG;
  ushort* ctx  = ws + 24 * MEG;
  ushort* S1   = ws + 28 * MEG;
  ushort* Wq  = ws + 32 * MEG; ushort* Wk  = ws + 33 * MEG; ushort* Wv  = ws + 34 * MEG;
  ushort* Wsq = ws + 35 * MEG; ushort* Wsk = ws + 36 * MEG; ushort* Wsv = ws + 37 * MEG;
  ushort* Wd  = ws + 38 * MEG;
  const int M = 4096, N = 1024, Kd = 1024;
  {
    CvtArgs ca;
    ca.s[0] = dec;  ca.d[0] = decb; ca.blks[0] = 4096;
    ca.s[1] = enc;  ca.d[1] = encb; ca.blks[1] = 4096;
    ca.s[2] = q_w;  ca.d[2] = Wq;   ca.blks[2] = 1024;
    ca.s[3] = k_w;  ca.d[3] = Wk;   ca.blks[3] = 1024;
    ca.s[4] = v_w;  ca.d[4] = Wv;   ca.blks[4] = 1024;
    ca.s[5] = sq_w; ca.d[5] = Wsq;  ca.blks[5] = 1024;
    ca.s[6] = sk_w; ca.d[6] = Wsk;  ca.blks[6] = 1024;
    ca.s[7] = sv_w; ca.d[7] = Wsv;  ca.blks[7] = 1024;
    ca.s[8] = dw;   ca.d[8] = Wd;   ca.blks[8] = 1024;
    cvtk_multi<<<15360, 256, 0, stream>>>(ca);
  }
  // ---- self attention ----
  {
    GemmArgs ga;
    ga.A[0] = decb; ga.A[1] = decb; ga.A[2] = decb;
    ga.W[0] = Wq;   ga.W[1] = Wk;   ga.W[2] = Wv;
    ga.bias[0] = q_b; ga.bias[1] = k_b; ga.bias[2] = v_b;
    ga.R[0] = nullptr; ga.R[1] = nullptr; ga.R[2] = nullptr;
    ga.C[0] = Qb;   ga.C[1] = Kb;   ga.C[2] = Vtb;
    ga.mode[0] = 0; ga.mode[1] = 0; ga.mode[2] = 2;
    ga.scale[0] = LOG2E; ga.scale[1] = 1.f; ga.scale[2] = 1.f;
    gemm128<<<768, 256, 0, stream>>>(ga, 3, N, Kd);
  }
  attn_kernel<<<1024, 256, 0, stream>>>(Qb, Kb, Vtb, ctx, nullptr, 1);
  {
    GemmArgs ga = {};
    ga.A[0] = ctx; ga.W[0] = Wd; ga.bias[0] = db; ga.R[0] = Qb; ga.C[0] = S1; ga.mode[0] = 1;
    ga.scale[0] = 1.f;
    gemm_bt<<<512, 256, 0, stream>>>(ga, 1, M, N, Kd);
  }
  ln_kernel<<<4096, 256, 0, stream>>>(S1, lng, lnb, decb, nullptr);
  // ---- cross attention ----
  {
    GemmArgs ga;
    ga.A[0] = decb; ga.A[1] = encb; ga.A[2] = encb;
    ga.W[0] = Wsq;  ga.W[1] = Wsk;  ga.W[2] = Wsv;
    ga.bias[0] = sq_b; ga.bias[1] = sk_b; ga.bias[2] = sv_b;
    ga.R[0] = nullptr; ga.R[1] = nullptr; ga.R[2] = nullptr;
    ga.C[0] = Qb;   ga.C[1] = Kb;   ga.C[2] = Vtb;
    ga.mode[0] = 0; ga.mode[1] = 0; ga.mode[2] = 2;
    ga.scale[0] = LOG2E; ga.scale[1] = 1.f; ga.scale[2] = 1.f;
    gemm128<<<768, 256, 0, stream>>>(ga, 3, N, Kd);
  }
  attn_kernel<<<1024, 256, 0, stream>>>(Qb, Kb, Vtb, ctx, smask, 0);
  {
    GemmArgs ga = {};
    ga.A[0] = ctx; ga.W[0] = Wd; ga.bias[0] = db; ga.R[0] = Qb; ga.C[0] = S1; ga.mode[0] = 1;
    ga.scale[0] = 1.f;
    gemm_bt<<<512, 256, 0, stream>>>(ga, 1, M, N, Kd);
  }
  ln_kernel<<<4096, 256, 0, stream>>>(S1, lng, lnb, nullptr, (float*)d_out);
}